// Round 9
// baseline (1000.344 us; speedup 1.0000x reference)
//
#include <hip/hip_runtime.h>
#include <hip/hip_bf16.h>

#define B_   32
#define M_   512
#define E_   512
#define S_   513            // M+1
#define T_   (B_ * S_)      // 16416 tokens
#define TP_  16512          // 129*128 padded
#define NH_  8
#define DH_  64
#define F_   768
#define DFF_ 2048

#define GMT_ 129            // m tiles

typedef short short8 __attribute__((ext_vector_type(8)));
typedef float floatx4 __attribute__((ext_vector_type(4)));

__device__ __forceinline__ float bf2f(unsigned short u) {
    return __uint_as_float(((unsigned int)u) << 16);
}
__device__ __forceinline__ unsigned short f2b_rne(float f) {
    unsigned int u = __float_as_uint(f);
    unsigned int r = u + 0x7FFF + ((u >> 16) & 1);
    return (unsigned short)(r >> 16);
}
__device__ __forceinline__ void gload16(const void* g, void* l) {
    __builtin_amdgcn_global_load_lds(
        (const __attribute__((address_space(1))) void*)g,
        (__attribute__((address_space(3))) void*)l, 16, 0, 0);
}

// ---------------------------------------------------------------- span ids
__global__ void span_kernel(const int* __restrict__ pos1, int* __restrict__ span) {
    int b = blockIdx.x;
    __shared__ int st[M_], en[M_];
    __shared__ int redm[4];
    int tid = threadIdx.x;
    for (int j = tid; j < M_; j += 256) {
        st[j] = pos1[(b * M_ + j) * 2];
        en[j] = pos1[(b * M_ + j) * 2 + 1];
    }
    __syncthreads();
    // parallel first-zero: min index j with en[j]==0 (prefix-validity semantics)
    int idx = M_;
    for (int j = tid; j < M_; j += 256)
        if (en[j] == 0 && j < idx) idx = j;
    for (int off = 32; off; off >>= 1) idx = min(idx, __shfl_down(idx, off));
    if ((tid & 63) == 0) redm[tid >> 6] = idx;
    __syncthreads();
    int n = min(min(redm[0], redm[1]), min(redm[2], redm[3]));
    for (int k = tid; k < M_; k += 256) {
        int best = -1;
        for (int j = 0; j < n; ++j)
            if (st[j] <= k && k < en[j]) best = j;
        span[b * M_ + k] = best;
    }
}

// ---------------------------------------------------------------- f32 -> bf16, 5 fused segments, x4 vectorized
__global__ void f2b5_kernel(const float* __restrict__ s0, const float* __restrict__ s1,
                            const float* __restrict__ s2, const float* __restrict__ s3,
                            const float* __restrict__ s4,
                            unsigned short* __restrict__ dst,
                            int c0, int c1, int c2, int c3, int c4) {
    int i = (blockIdx.x * 256 + threadIdx.x) * 4;
    if (i >= c4) return;
    const float* src;
    if      (i < c0) src = s0 + i;
    else if (i < c1) src = s1 + (i - c0);
    else if (i < c2) src = s2 + (i - c1);
    else if (i < c3) src = s3 + (i - c2);
    else             src = s4 + (i - c3);
    float4 v = *(const float4*)src;
    ushort4 o;
    o.x = f2b_rne(v.x); o.y = f2b_rne(v.y); o.z = f2b_rne(v.z); o.w = f2b_rne(v.w);
    *(ushort4*)&dst[i] = o;
}

// ---------------------------------------------------------------- build x0 (f32 + bf16 shadow), PE inline
__global__ __launch_bounds__(256) void build_x(const float* __restrict__ emb,
                        const int* __restrict__ pos2,
                        const float* __restrict__ fbase,
                        const int* __restrict__ span,
                        float* __restrict__ x,
                        unsigned short* __restrict__ xb) {
    int gid = blockIdx.x * 256 + threadIdx.x;      // 0 .. T_*64-1
    int t  = gid >> 6;                              // token
    int e0 = (gid & 63) * 8;                        // first of 8 elems
    int s = t % S_;
    int b = t / S_;
    float v[8];
    if (s == 0) {
        float4 a = *(const float4*)&emb[E_ + e0];
        float4 c = *(const float4*)&emb[E_ + e0 + 4];
        v[0]=a.x; v[1]=a.y; v[2]=a.z; v[3]=a.w; v[4]=c.x; v[5]=c.y; v[6]=c.z; v[7]=c.w;
    } else {
        int k = s - 1;
        int sid = span[b * M_ + k];
        if (sid >= 0) {
            int p = pos2[b * M_ + sid];
            const float* er = emb + (size_t)p * E_ + e0;
            float4 a = *(const float4*)er;
            float4 c = *(const float4*)(er + 4);
            v[0]=a.x; v[1]=a.y; v[2]=a.z; v[3]=a.w; v[4]=c.x; v[5]=c.y; v[6]=c.z; v[7]=c.w;
            float fs = (float)sid;
#pragma unroll
            for (int jj = 0; jj < 4; ++jj) {
                float ex = (float)(e0 + 2 * jj) * (1.0f / 512.0f);
                float ang = fs * exp2f(-ex * 13.287712379549449f);   // log2(10000)
                float sn, cs;
                __sincosf(ang, &sn, &cs);
                v[2 * jj]     += sn;
                v[2 * jj + 1] += cs;
            }
        } else {
            const float* fr = fbase + ((size_t)b * M_ + k) * E_ + e0;
            float4 a = *(const float4*)fr;
            float4 c = *(const float4*)(fr + 4);
            v[0]=a.x; v[1]=a.y; v[2]=a.z; v[3]=a.w; v[4]=c.x; v[5]=c.y; v[6]=c.z; v[7]=c.w;
        }
    }
    size_t o = (size_t)t * E_ + e0;
    *(float4*)&x[o]     = make_float4(v[0], v[1], v[2], v[3]);
    *(float4*)&x[o + 4] = make_float4(v[4], v[5], v[6], v[7]);
    short8 ob;
#pragma unroll
    for (int j = 0; j < 8; ++j) ob[j] = (short)f2b_rne(v[j]);
    *(short8*)&xb[o] = ob;
}

// ---------------------------------------------------------------- bf16 MFMA GEMM (NT)
// LDS-bandwidth fix over the R8 body: A-fragments load DIRECTLY from global to
// registers (per row the 4 fq-lanes read one 64B-aligned line; the 8KB per-step
// A-slice is L1-resident, re-read only within the block - addressing verified in
// R5's reg-GEMM). B keeps the verified 3-buffer LDS + counted-vmcnt + both-sides
// chunk-XOR swizzle path (zero conflicts, R1/R8). LDS traffic per block-step
// halves (48->24 KB) and LDS shrinks 48->24 KB -> 4 blocks/CU (was 3).
// Load-order discipline: af-loads BEFORE the stage issue + sched_barrier(0) so
// the compiler's pre-MFMA wait is vmcnt(2) (stage stays in flight), not vmcnt(0).
// ACT==2 fuses the discriminator pos-feature dot (no C store).
template <int ACT, int KT>  // ACT: 0 none 1 relu 2 tanh+zdot(no C write)
__global__ __launch_bounds__(256, 4) void gemm_bf16(const unsigned short* __restrict__ A,
                                                    const unsigned short* __restrict__ W,
                                                    const float* __restrict__ bias,
                                                    unsigned short* __restrict__ Cb,
                                                    int T, int O,
                                                    const float* __restrict__ wdz,
                                                    float* __restrict__ zout) {
    constexpr int K = KT;
    constexpr int NSTEP = K / 32;
    __shared__ __align__(16) unsigned short sB[3][128 * 32];   // 24 KB
    int tid = threadIdx.x;
    int lane = tid & 63, wv = tid >> 6;
    int wr = (wv >> 1) * 64, wc = (wv & 1) * 64;

    // ---- panel swizzle: 8 m-tiles per panel, n fastest within panel
    int gn = O / 128;
    int per_panel = 8 * gn;
    int id = blockIdx.x;
    int p = id / per_panel;
    int r = id - p * per_panel;
    int mrem = GMT_ - p * 8; if (mrem > 8) mrem = 8;
    int mt = p * 8 + r % mrem;
    int nt = r / mrem;
    int t0 = mt * 128, o0 = nt * 128;

    floatx4 acc[4][4] = {};

    int fr = lane & 15;
    int fq = lane >> 4;

    // A fragments: direct global (no LDS). Per step kt, lane reads 16B at
    // (t0+wr+i*16+fr)*K + kt*32 + fq*8  -> 4 lanes/row cover one 64B line.
    const unsigned short* Af = A + (size_t)(t0 + wr + fr) * K + fq * 8;

    // B staging (unchanged, verified): global chunk pre-swizzled, LDS linear dest.
    int swz_st = (((lane & 3) ^ ((lane >> 3) & 3))) * 8;
    const unsigned short* Bg = W + (size_t)(o0 + wv * 32 + (lane >> 2)) * K + swz_st;
    const size_t row16 = (size_t)16 * K;
    const int wvo = wv * 1024;
    // fragment read: row = wc + j*16 + fr; chunk = fq ^ ((fr>>1)&3)
    int fks = ((fq ^ ((lane >> 1) & 3))) * 8;

    auto stage = [&](unsigned short* db, int k) {
        gload16(Bg + k, db + wvo);
        gload16(Bg + row16 + k, db + wvo + 512);
    };

    unsigned short *b0 = sB[0], *b1 = sB[1], *b2 = sB[2];

    // prologue: 2 B-stages in flight (4 vm ops/wave)
    stage(b0, 0);
    stage(b1, 32);

#pragma unroll 2
    for (int t = 0; t < NSTEP - 2; ++t) {
        asm volatile("s_waitcnt vmcnt(2)" ::: "memory");   // stage(t) landed
        __builtin_amdgcn_s_barrier();
        asm volatile("" ::: "memory");
        // A-frag loads FIRST (so they retire before the newly-issued stage)
        short8 af[4];
#pragma unroll
        for (int i = 0; i < 4; ++i)
            af[i] = *(const short8*)(Af + (size_t)i * 16 * K + t * 32);
        __builtin_amdgcn_sched_barrier(0);
        stage(b2, (t + 2) * 32);   // slot (t-1)%3: all reads done pre-barrier
        short8 bfr[4];
#pragma unroll
        for (int j = 0; j < 4; ++j)
            bfr[j] = *(const short8*)&b0[(wc + j * 16 + fr) * 32 + fks];
        __builtin_amdgcn_s_setprio(1);
#pragma unroll
        for (int i = 0; i < 4; ++i)
#pragma unroll
            for (int j = 0; j < 4; ++j)
                acc[i][j] = __builtin_amdgcn_mfma_f32_16x16x32_bf16(af[i], bfr[j], acc[i][j], 0, 0, 0);
        __builtin_amdgcn_s_setprio(0);
        unsigned short* tb = b0; b0 = b1; b1 = b2; b2 = tb;
    }
    // t = NSTEP-2: stage(NSTEP-1) may still be in flight
    asm volatile("s_waitcnt vmcnt(2)" ::: "memory");
    __builtin_amdgcn_s_barrier();
    asm volatile("" ::: "memory");
    {
        short8 af[4], bfr[4];
#pragma unroll
        for (int i = 0; i < 4; ++i)
            af[i] = *(const short8*)(Af + (size_t)i * 16 * K + (NSTEP - 2) * 32);
#pragma unroll
        for (int j = 0; j < 4; ++j)
            bfr[j] = *(const short8*)&b0[(wc + j * 16 + fr) * 32 + fks];
#pragma unroll
        for (int i = 0; i < 4; ++i)
#pragma unroll
            for (int j = 0; j < 4; ++j)
                acc[i][j] = __builtin_amdgcn_mfma_f32_16x16x32_bf16(af[i], bfr[j], acc[i][j], 0, 0, 0);
    }
    // t = NSTEP-1: full drain (only place vmcnt reaches 0)
    asm volatile("s_waitcnt vmcnt(0)" ::: "memory");
    __builtin_amdgcn_s_barrier();
    asm volatile("" ::: "memory");
    {
        short8 af[4], bfr[4];
#pragma unroll
        for (int i = 0; i < 4; ++i)
            af[i] = *(const short8*)(Af + (size_t)i * 16 * K + (NSTEP - 1) * 32);
#pragma unroll
        for (int j = 0; j < 4; ++j)
            bfr[j] = *(const short8*)&b1[(wc + j * 16 + fr) * 32 + fks];
#pragma unroll
        for (int i = 0; i < 4; ++i)
#pragma unroll
            for (int j = 0; j < 4; ++j)
                acc[i][j] = __builtin_amdgcn_mfma_f32_16x16x32_bf16(af[i], bfr[j], acc[i][j], 0, 0, 0);
    }

    int cr = fq * 4;
    int cc = fr;
    if (ACT == 2) {
        // fused tanh + z-dot epilogue: zp[i][rr] = sum_j tanh(acc) * wdz[col]
        float zp[4][4];
#pragma unroll
        for (int i = 0; i < 4; ++i)
#pragma unroll
            for (int rr = 0; rr < 4; ++rr) zp[i][rr] = 0.f;
#pragma unroll
        for (int j = 0; j < 4; ++j) {
            int gn_ = o0 + wc + j * 16 + cc;
            float wz = wdz[gn_];
#pragma unroll
            for (int i = 0; i < 4; ++i)
#pragma unroll
                for (int rr = 0; rr < 4; ++rr)
                    zp[i][rr] += tanhf(acc[i][j][rr]) * wz;
        }
#pragma unroll
        for (int i = 0; i < 4; ++i)
#pragma unroll
            for (int rr = 0; rr < 4; ++rr) {
                float v = zp[i][rr];
                v += __shfl_xor(v, 1);
                v += __shfl_xor(v, 2);
                v += __shfl_xor(v, 4);
                v += __shfl_xor(v, 8);
                if (cc == 0) {
                    int gm_ = t0 + wr + i * 16 + cr + rr;
                    if (gm_ < T) atomicAdd(&zout[gm_], v);
                }
            }
        return;
    }
#pragma unroll
    for (int i = 0; i < 4; ++i) {
#pragma unroll
        for (int j = 0; j < 4; ++j) {
            int gn_ = o0 + wc + j * 16 + cc;
            float bv = bias ? bias[gn_] : 0.f;
#pragma unroll
            for (int rr = 0; rr < 4; ++rr) {
                int gm_ = t0 + wr + i * 16 + cr + rr;
                if (gm_ >= T) continue;
                float v = acc[i][j][rr] + bv;
                if (ACT == 1) v = fmaxf(v, 0.f);
                Cb[(size_t)gm_ * O + gn_] = f2b_rne(v);
            }
        }
    }
}

// ---------------------------------------------------------------- MFMA attention: one wave per (s,h)
__global__ __launch_bounds__(64) void attn_mfma(const unsigned short* __restrict__ qkv,
                                                unsigned short* __restrict__ o) {
    __shared__ __align__(16) unsigned short vt[64 * 40];   // V^T [d][m], stride 40
    __shared__ __align__(16) unsigned short ps[32 * 40];   // P [l][m], stride 40
    int s = blockIdx.x, h = blockIdx.y;
    int lane = threadIdx.x;
    int hd = h * 64;
    int fr = lane & 15, fq = lane >> 4;

    {
        int m = lane >> 1;
        int d0 = (lane & 1) * 32;
        const unsigned short* vrow = qkv + ((size_t)m * S_ + s) * 1536 + 1024 + hd + d0;
        short8 v0 = *(const short8*)(vrow);
        short8 v1 = *(const short8*)(vrow + 8);
        short8 v2 = *(const short8*)(vrow + 16);
        short8 v3 = *(const short8*)(vrow + 24);
#pragma unroll
        for (int j = 0; j < 8; ++j) {
            vt[(d0 + j) * 40 + m]      = (unsigned short)v0[j];
            vt[(d0 + 8 + j) * 40 + m]  = (unsigned short)v1[j];
            vt[(d0 + 16 + j) * 40 + m] = (unsigned short)v2[j];
            vt[(d0 + 24 + j) * 40 + m] = (unsigned short)v3[j];
        }
    }

    floatx4 c[2][2] = {};
#pragma unroll
    for (int ks = 0; ks < 2; ++ks) {
        short8 aq[2], bk[2];
#pragma unroll
        for (int lt = 0; lt < 2; ++lt) {
            int l = lt * 16 + fr;
            aq[lt] = *(const short8*)(qkv + ((size_t)l * S_ + s) * 1536 + hd + ks * 32 + fq * 8);
        }
#pragma unroll
        for (int mt = 0; mt < 2; ++mt) {
            int m = mt * 16 + fr;
            bk[mt] = *(const short8*)(qkv + ((size_t)m * S_ + s) * 1536 + 512 + hd + ks * 32 + fq * 8);
        }
#pragma unroll
        for (int lt = 0; lt < 2; ++lt)
#pragma unroll
            for (int mt = 0; mt < 2; ++mt)
                c[lt][mt] = __builtin_amdgcn_mfma_f32_16x16x32_bf16(aq[lt], bk[mt], c[lt][mt], 0, 0, 0);
    }

#pragma unroll
    for (int lt = 0; lt < 2; ++lt) {
#pragma unroll
        for (int r = 0; r < 4; ++r) {
            float a = c[lt][0][r] * 0.125f;
            float b = c[lt][1][r] * 0.125f;
            float mx = fmaxf(a, b);
#pragma unroll
            for (int off = 1; off < 16; off <<= 1) mx = fmaxf(mx, __shfl_xor(mx, off));
            float ea = expf(a - mx), eb = expf(b - mx);
            float sm = ea + eb;
#pragma unroll
            for (int off = 1; off < 16; off <<= 1) sm += __shfl_xor(sm, off);
            float inv = 1.f / sm;
            int l = lt * 16 + fq * 4 + r;
            ps[l * 40 + fr]      = f2b_rne(ea * inv);
            ps[l * 40 + 16 + fr] = f2b_rne(eb * inv);
        }
    }
    __syncthreads();

    short8 pa[2], vb[4];
#pragma unroll
    for (int lt = 0; lt < 2; ++lt)
        pa[lt] = *(const short8*)&ps[(lt * 16 + fr) * 40 + fq * 8];
#pragma unroll
    for (int dt = 0; dt < 4; ++dt)
        vb[dt] = *(const short8*)&vt[(dt * 16 + fr) * 40 + fq * 8];

    floatx4 oa[2][4] = {};
#pragma unroll
    for (int lt = 0; lt < 2; ++lt)
#pragma unroll
        for (int dt = 0; dt < 4; ++dt)
            oa[lt][dt] = __builtin_amdgcn_mfma_f32_16x16x32_bf16(pa[lt], vb[dt], oa[lt][dt], 0, 0, 0);

#pragma unroll
    for (int lt = 0; lt < 2; ++lt)
#pragma unroll
        for (int dt = 0; dt < 4; ++dt)
#pragma unroll
            for (int r = 0; r < 4; ++r) {
                int l = lt * 16 + fq * 4 + r;
                o[((size_t)l * S_ + s) * E_ + hd + dt * 16 + fr] = f2b_rne(oa[lt][dt][r]);
            }
}

// ---------------------------------------------------------------- x = LN(x + h); wave-per-token (64 lanes x 8 elems)
// WX=false skips the f32 x write (dead after the last LN - only xb is read later).
template <bool WX>
__global__ __launch_bounds__(256) void add_ln(float* __restrict__ x,
                                              unsigned short* __restrict__ xb,
                                              const unsigned short* __restrict__ h,
                                              const float* __restrict__ w,
                                              const float* __restrict__ b) {
    int t = (blockIdx.x << 2) + (threadIdx.x >> 6);   // token (grid = T_/4 blocks)
    int lane = threadIdx.x & 63;
    int i0 = lane * 8;
    float* xr = x + (size_t)t * E_;
    const unsigned short* hr = h + (size_t)t * E_;
    float4 xv0 = *(const float4*)&xr[i0];
    float4 xv1 = *(const float4*)&xr[i0 + 4];
    short8 hv = *(const short8*)&hr[i0];
    float v[8];
    v[0] = xv0.x + bf2f((unsigned short)hv[0]);
    v[1] = xv0.y + bf2f((unsigned short)hv[1]);
    v[2] = xv0.z + bf2f((unsigned short)hv[2]);
    v[3] = xv0.w + bf2f((unsigned short)hv[3]);
    v[4] = xv1.x + bf2f((unsigned short)hv[4]);
    v[5] = xv1.y + bf2f((unsigned short)hv[5]);
    v[6] = xv1.z + bf2f((unsigned short)hv[6]);
    v[7] = xv1.w + bf2f((unsigned short)hv[7]);

    float sum = 0.f;
#pragma unroll
    for (int j = 0; j < 8; ++j) sum += v[j];
#pragma unroll
    for (int off = 32; off; off >>= 1) sum += __shfl_xor(sum, off);
    float mu = sum * (1.0f / E_);

    float qs = 0.f;
#pragma unroll
    for (int j = 0; j < 8; ++j) { float d = v[j] - mu; qs += d * d; }
#pragma unroll
    for (int off = 32; off; off >>= 1) qs += __shfl_xor(qs, off);
    float rstd = rsqrtf(qs * (1.0f / E_) + 1e-5f);

    float4 wv0 = *(const float4*)&w[i0];
    float4 wv1 = *(const float4*)&w[i0 + 4];
    float4 bv0 = *(const float4*)&b[i0];
    float4 bv1 = *(const float4*)&b[i0 + 4];
    float o[8];
    o[0] = (v[0] - mu) * rstd * wv0.x + bv0.x;
    o[1] = (v[1] - mu) * rstd * wv0.y + bv0.y;
    o[2] = (v[2] - mu) * rstd * wv0.z + bv0.z;
    o[3] = (v[3] - mu) * rstd * wv0.w + bv0.w;
    o[4] = (v[4] - mu) * rstd * wv1.x + bv1.x;
    o[5] = (v[5] - mu) * rstd * wv1.y + bv1.y;
    o[6] = (v[6] - mu) * rstd * wv1.z + bv1.z;
    o[7] = (v[7] - mu) * rstd * wv1.w + bv1.w;
    if (WX) {
        *(float4*)&xr[i0]     = make_float4(o[0], o[1], o[2], o[3]);
        *(float4*)&xr[i0 + 4] = make_float4(o[4], o[5], o[6], o[7]);
    }
    short8 ob;
#pragma unroll
    for (int j = 0; j < 8; ++j) ob[j] = (short)f2b_rne(o[j]);
    *(short8*)&xb[(size_t)t * E_ + i0] = ob;
}

// ---------------------------------------------------------------- discriminator + sigmoid, wave-per-token
__global__ __launch_bounds__(256) void disc_kernel(const float* __restrict__ bert,
                                                   const float* __restrict__ z,
                                                   const float* __restrict__ wd,
                                                   const float* __restrict__ bd,
                                                   float* __restrict__ out) {
    int t = (blockIdx.x << 2) + (threadIdx.x >> 6);   // grid = T_/4 blocks
    int lane = threadIdx.x & 63;
    int i0 = lane * 12;                               // 64 * 12 = 768
    const float* br = bert + (size_t)t * F_ + i0;
    const float* wr = wd + i0;
    float s = 0.f;
#pragma unroll
    for (int j = 0; j < 12; j += 4) {
        float4 bv = *(const float4*)(br + j);
        float4 wv = *(const float4*)(wr + j);
        s += bv.x * wv.x + bv.y * wv.y + bv.z * wv.z + bv.w * wv.w;
    }
#pragma unroll
    for (int off = 32; off; off >>= 1) s += __shfl_xor(s, off);
    if (lane == 0) {
        float zz = s + z[t] + bd[0];
        out[t] = 1.f / (1.f + expf(-zz));
    }
}

// ---------------------------------------------------------------- launch
extern "C" void kernel_launch(void* const* d_in, const int* in_sizes, int n_in,
                              void* d_out, int out_size, void* d_ws, size_t ws_size,
                              hipStream_t stream) {
    const int*   pos1 = (const int*)d_in[0];
    const int*   pos2 = (const int*)d_in[1];
    const float* bert = (const float*)d_in[2];
    const float* fb   = (const float*)d_in[3];
    const float* emb  = (const float*)d_in[4];
    const float* wi   = (const float*)d_in[5];
    const float* bi   = (const float*)d_in[6];
    const float* wo   = (const float*)d_in[7];
    const float* bo   = (const float*)d_in[8];
    const float* ln1w = (const float*)d_in[9];
    const float* ln1b = (const float*)d_in[10];
    const float* ln2w = (const float*)d_in[11];
    const float* ln2b = (const float*)d_in[12];
    const float* w1   = (const float*)d_in[13];
    const float* b1   = (const float*)d_in[14];
    const float* w2   = (const float*)d_in[15];
    const float* b2   = (const float*)d_in[16];
    const float* wm   = (const float*)d_in[17];
    const float* wd   = (const float*)d_in[18];
    const float* bd   = (const float*)d_in[19];
    float* out = (float*)d_out;

    // workspace layout
    float* ws   = (float*)d_ws;
    int*   span = (int*)ws;                                   // 16384 i
    float* x    = ws + 16384;                                 // T_*512 f
    unsigned short* xb  = (unsigned short*)(x + (size_t)T_ * 512);   // TP_*512 bf16
    unsigned short* atb = xb + (size_t)TP_ * 512;                    // TP_*512 bf16
    unsigned short* hb  = atb + (size_t)TP_ * 512;                   // T_*512 bf16
    unsigned short* U   = hb + (size_t)T_ * 512;              // union: qkv | h1
    unsigned short* qkvb = U;
    unsigned short* h1b  = U;
    unsigned short* wib  = U + (size_t)TP_ * 2048;            // weights bf16, contiguous
    const int NWI = 2 * 1536 * 512;
    const int NWO = 2 * 512 * 512;
    const int NW1 = 2 * 2048 * 512;
    const int NW2 = 2 * 512 * 2048;
    const int NWM = 768 * 512;
    unsigned short* wob = wib + NWI;
    unsigned short* w1b = wob + NWO;
    unsigned short* w2b = w1b + NW1;
    unsigned short* wmb = w2b + NW2;
    // z (T_ f32) aliases atb: atb is dead after the layer-2 WO GEMM reads it.
    float* z = (float*)atb;

    span_kernel<<<B_, 256, 0, stream>>>(pos1, span);
    {
        int c0 = NWI, c1 = c0 + NWO, c2 = c1 + NW1, c3 = c2 + NW2, c4 = c3 + NWM;
        f2b5_kernel<<<(c4 / 4 + 255) / 256, 256, 0, stream>>>(wi, wo, w1, w2, wm, wib,
                                                              c0, c1, c2, c3, c4);
    }
    build_x<<<T_ / 4, 256, 0, stream>>>(emb, pos2, fb, span, x, xb);

    for (int l = 0; l < 2; ++l) {
        gemm_bf16<0, 512><<<GMT_ * (1536 / 128), 256, 0, stream>>>(
            xb, wib + (size_t)l * 1536 * 512, bi + l * 1536, qkvb, T_, 1536, nullptr, nullptr);
        attn_mfma<<<dim3(S_, NH_), 64, 0, stream>>>(qkvb, atb);
        gemm_bf16<0, 512><<<GMT_ * (512 / 128), 256, 0, stream>>>(
            atb, wob + (size_t)l * 512 * 512, bo + l * 512, hb, T_, 512, nullptr, nullptr);
        add_ln<true><<<T_ / 4, 256, 0, stream>>>(x, xb, hb, ln1w + l * 512, ln1b + l * 512);
        gemm_bf16<1, 512><<<GMT_ * (2048 / 128), 256, 0, stream>>>(
            xb, w1b + (size_t)l * 2048 * 512, b1 + l * 2048, h1b, T_, 2048, nullptr, nullptr);
        gemm_bf16<0, 2048><<<GMT_ * (512 / 128), 256, 0, stream>>>(
            h1b, w2b + (size_t)l * 512 * 2048, b2 + l * 512, hb, T_, 512, nullptr, nullptr);
        if (l == 0)
            add_ln<true><<<T_ / 4, 256, 0, stream>>>(x, xb, hb, ln2w + l * 512, ln2b + l * 512);
        else
            add_ln<false><<<T_ / 4, 256, 0, stream>>>(x, xb, hb, ln2w + l * 512, ln2b + l * 512);
    }
    // atb now dead -> reuse as z accumulator for the fused final GEMM + disc dot
    hipMemsetAsync(z, 0, (size_t)T_ * sizeof(float), stream);
    gemm_bf16<2, 512><<<GMT_ * (768 / 128), 256, 0, stream>>>(
        xb, wmb, nullptr, nullptr, T_, 768, wd + F_, z);
    disc_kernel<<<T_ / 4, 256, 0, stream>>>(bert, z, wd, bd, out);
}

// Round 10
// 728.910 us; speedup vs baseline: 1.3724x; 1.3724x over previous
//
#include <hip/hip_runtime.h>
#include <hip/hip_bf16.h>

#define B_   32
#define M_   512
#define E_   512
#define S_   513            // M+1
#define T_   (B_ * S_)      // 16416 tokens
#define TP_  16512          // 129*128 padded
#define NH_  8
#define DH_  64
#define F_   768
#define DFF_ 2048

#define GMT_ 129            // m tiles

typedef short short8 __attribute__((ext_vector_type(8)));
typedef float floatx4 __attribute__((ext_vector_type(4)));

__device__ __forceinline__ float bf2f(unsigned short u) {
    return __uint_as_float(((unsigned int)u) << 16);
}
__device__ __forceinline__ unsigned short f2b_rne(float f) {
    unsigned int u = __float_as_uint(f);
    unsigned int r = u + 0x7FFF + ((u >> 16) & 1);
    return (unsigned short)(r >> 16);
}
__device__ __forceinline__ void gload16(const void* g, void* l) {
    __builtin_amdgcn_global_load_lds(
        (const __attribute__((address_space(1))) void*)g,
        (__attribute__((address_space(3))) void*)l, 16, 0, 0);
}

// ---------------------------------------------------------------- span ids
__global__ void span_kernel(const int* __restrict__ pos1, int* __restrict__ span) {
    int b = blockIdx.x;
    __shared__ int st[M_], en[M_];
    __shared__ int redm[4];
    int tid = threadIdx.x;
    for (int j = tid; j < M_; j += 256) {
        st[j] = pos1[(b * M_ + j) * 2];
        en[j] = pos1[(b * M_ + j) * 2 + 1];
    }
    __syncthreads();
    // parallel first-zero: min index j with en[j]==0 (prefix-validity semantics)
    int idx = M_;
    for (int j = tid; j < M_; j += 256)
        if (en[j] == 0 && j < idx) idx = j;
    for (int off = 32; off; off >>= 1) idx = min(idx, __shfl_down(idx, off));
    if ((tid & 63) == 0) redm[tid >> 6] = idx;
    __syncthreads();
    int n = min(min(redm[0], redm[1]), min(redm[2], redm[3]));
    for (int k = tid; k < M_; k += 256) {
        int best = -1;
        for (int j = 0; j < n; ++j)
            if (st[j] <= k && k < en[j]) best = j;
        span[b * M_ + k] = best;
    }
}

// ---------------------------------------------------------------- f32 -> bf16, 5 fused segments, x4 vectorized
__global__ void f2b5_kernel(const float* __restrict__ s0, const float* __restrict__ s1,
                            const float* __restrict__ s2, const float* __restrict__ s3,
                            const float* __restrict__ s4,
                            unsigned short* __restrict__ dst,
                            int c0, int c1, int c2, int c3, int c4) {
    int i = (blockIdx.x * 256 + threadIdx.x) * 4;
    if (i >= c4) return;
    const float* src;
    if      (i < c0) src = s0 + i;
    else if (i < c1) src = s1 + (i - c0);
    else if (i < c2) src = s2 + (i - c1);
    else if (i < c3) src = s3 + (i - c2);
    else             src = s4 + (i - c3);
    float4 v = *(const float4*)src;
    ushort4 o;
    o.x = f2b_rne(v.x); o.y = f2b_rne(v.y); o.z = f2b_rne(v.z); o.w = f2b_rne(v.w);
    *(ushort4*)&dst[i] = o;
}

// ---------------------------------------------------------------- build x0 (f32 + bf16 shadow), PE inline
__global__ __launch_bounds__(256) void build_x(const float* __restrict__ emb,
                        const int* __restrict__ pos2,
                        const float* __restrict__ fbase,
                        const int* __restrict__ span,
                        float* __restrict__ x,
                        unsigned short* __restrict__ xb) {
    int gid = blockIdx.x * 256 + threadIdx.x;      // 0 .. T_*64-1
    int t  = gid >> 6;                              // token
    int e0 = (gid & 63) * 8;                        // first of 8 elems
    int s = t % S_;
    int b = t / S_;
    float v[8];
    if (s == 0) {
        float4 a = *(const float4*)&emb[E_ + e0];
        float4 c = *(const float4*)&emb[E_ + e0 + 4];
        v[0]=a.x; v[1]=a.y; v[2]=a.z; v[3]=a.w; v[4]=c.x; v[5]=c.y; v[6]=c.z; v[7]=c.w;
    } else {
        int k = s - 1;
        int sid = span[b * M_ + k];
        if (sid >= 0) {
            int p = pos2[b * M_ + sid];
            const float* er = emb + (size_t)p * E_ + e0;
            float4 a = *(const float4*)er;
            float4 c = *(const float4*)(er + 4);
            v[0]=a.x; v[1]=a.y; v[2]=a.z; v[3]=a.w; v[4]=c.x; v[5]=c.y; v[6]=c.z; v[7]=c.w;
            float fs = (float)sid;
#pragma unroll
            for (int jj = 0; jj < 4; ++jj) {
                float ex = (float)(e0 + 2 * jj) * (1.0f / 512.0f);
                float ang = fs * exp2f(-ex * 13.287712379549449f);   // log2(10000)
                float sn, cs;
                __sincosf(ang, &sn, &cs);
                v[2 * jj]     += sn;
                v[2 * jj + 1] += cs;
            }
        } else {
            const float* fr = fbase + ((size_t)b * M_ + k) * E_ + e0;
            float4 a = *(const float4*)fr;
            float4 c = *(const float4*)(fr + 4);
            v[0]=a.x; v[1]=a.y; v[2]=a.z; v[3]=a.w; v[4]=c.x; v[5]=c.y; v[6]=c.z; v[7]=c.w;
        }
    }
    size_t o = (size_t)t * E_ + e0;
    *(float4*)&x[o]     = make_float4(v[0], v[1], v[2], v[3]);
    *(float4*)&x[o + 4] = make_float4(v[4], v[5], v[6], v[7]);
    short8 ob;
#pragma unroll
    for (int j = 0; j < 8; ++j) ob[j] = (short)f2b_rne(v[j]);
    *(short8*)&xb[o] = ob;
}

// ---------------------------------------------------------------- bf16 MFMA GEMM (NT)
// R8-verified body (best measured: FFN1-class 71.6 us, zero bank conflicts):
// 3 LDS buffers, counted s_waitcnt vmcnt(4) (stage(t+1) stays in flight across
// the barrier; vmcnt(0) only at the last peeled step), chunk-XOR swizzle on BOTH
// sides (pre-swizzled per-lane global source for the linear global_load_lds dest
// + same XOR on ds_read), setprio(1) around the MFMA cluster.
// FOUR falsified departures this session (bigger tile R3, 8-phase R4, no-LDS R5,
// A-from-global R9) - do not restructure further.
// ACT==2 fuses the discriminator pos-feature dot (no C store).
template <int ACT, int KT>  // ACT: 0 none 1 relu 2 tanh+zdot(no C write)
__global__ __launch_bounds__(256, 3) void gemm_bf16(const unsigned short* __restrict__ A,
                                                    const unsigned short* __restrict__ W,
                                                    const float* __restrict__ bias,
                                                    unsigned short* __restrict__ Cb,
                                                    int T, int O,
                                                    const float* __restrict__ wdz,
                                                    float* __restrict__ zout) {
    constexpr int K = KT;
    constexpr int NSTEP = K / 32;
    __shared__ __align__(16) unsigned short sA[3][128 * 32];
    __shared__ __align__(16) unsigned short sB[3][128 * 32];
    int tid = threadIdx.x;
    int lane = tid & 63, wv = tid >> 6;
    int wr = (wv >> 1) * 64, wc = (wv & 1) * 64;

    // ---- panel swizzle: 8 m-tiles per panel, n fastest within panel
    int gn = O / 128;
    int per_panel = 8 * gn;
    int id = blockIdx.x;
    int p = id / per_panel;
    int r = id - p * per_panel;
    int mrem = GMT_ - p * 8; if (mrem > 8) mrem = 8;
    int mt = p * 8 + r % mrem;
    int nt = r / mrem;
    int t0 = mt * 128, o0 = nt * 128;

    floatx4 acc[4][4] = {};

    // staging: lane covers row (lane>>2), chunk (lane&3); global chunk pre-swizzled
    // with s(row) = (row>>1)&3 == (lane>>3)&3 (same for row+16).
    int swz_st = (((lane & 3) ^ ((lane >> 3) & 3))) * 8;
    const unsigned short* Ag = A + (size_t)(t0 + wv * 32 + (lane >> 2)) * K + swz_st;
    const unsigned short* Bg = W + (size_t)(o0 + wv * 32 + (lane >> 2)) * K + swz_st;
    const size_t row16 = (size_t)16 * K;
    const int wvo = wv * 1024;

    // fragment read: row = (wr|wc) + i*16 + fr; chunk = fq ^ ((fr>>1)&3)
    int fr = lane & 15;
    int fks = (((lane >> 4) ^ ((lane >> 1) & 3))) * 8;

    auto stage = [&](unsigned short* da, unsigned short* db, int k) {
        gload16(Ag + k, da + wvo);
        gload16(Ag + row16 + k, da + wvo + 512);
        gload16(Bg + k, db + wvo);
        gload16(Bg + row16 + k, db + wvo + 512);
    };
    auto compute = [&](const unsigned short* ca, const unsigned short* cb) {
        short8 af[4], bfr[4];
#pragma unroll
        for (int i = 0; i < 4; ++i)
            af[i] = *(const short8*)&ca[(wr + i * 16 + fr) * 32 + fks];
#pragma unroll
        for (int j = 0; j < 4; ++j)
            bfr[j] = *(const short8*)&cb[(wc + j * 16 + fr) * 32 + fks];
        __builtin_amdgcn_s_setprio(1);
#pragma unroll
        for (int i = 0; i < 4; ++i)
#pragma unroll
            for (int j = 0; j < 4; ++j)
                acc[i][j] = __builtin_amdgcn_mfma_f32_16x16x32_bf16(af[i], bfr[j], acc[i][j], 0, 0, 0);
        __builtin_amdgcn_s_setprio(0);
    };

    unsigned short *a0 = sA[0], *a1 = sA[1], *a2 = sA[2];
    unsigned short *b0 = sB[0], *b1 = sB[1], *b2 = sB[2];

    // prologue: 2 stages in flight (8 vm ops/wave)
    stage(a0, b0, 0);
    stage(a1, b1, 32);

#pragma unroll 3
    for (int t = 0; t < NSTEP - 2; ++t) {
        // wait stage(t) only; stage(t+1)'s 4 loads stay in flight across the barrier
        asm volatile("s_waitcnt vmcnt(4)" ::: "memory");
        __builtin_amdgcn_s_barrier();
        asm volatile("" ::: "memory");
        stage(a2, b2, (t + 2) * 32);   // overwrites slot (t-1)%3: all reads of it done pre-barrier
        compute(a0, b0);
        unsigned short* ta = a0; a0 = a1; a1 = a2; a2 = ta;
        unsigned short* tb = b0; b0 = b1; b1 = b2; b2 = tb;
    }
    // t = NSTEP-2: stage(NSTEP-1) may still be in flight
    asm volatile("s_waitcnt vmcnt(4)" ::: "memory");
    __builtin_amdgcn_s_barrier();
    asm volatile("" ::: "memory");
    compute(a0, b0);
    a0 = a1; b0 = b1;
    // t = NSTEP-1: full drain (only place vmcnt reaches 0)
    asm volatile("s_waitcnt vmcnt(0)" ::: "memory");
    __builtin_amdgcn_s_barrier();
    asm volatile("" ::: "memory");
    compute(a0, b0);

    int cr = (lane >> 4) * 4;
    int cc = lane & 15;
    if (ACT == 2) {
        // fused tanh + z-dot epilogue: zp[i][rr] = sum_j tanh(acc) * wdz[col]
        float zp[4][4];
#pragma unroll
        for (int i = 0; i < 4; ++i)
#pragma unroll
            for (int rr = 0; rr < 4; ++rr) zp[i][rr] = 0.f;
#pragma unroll
        for (int j = 0; j < 4; ++j) {
            int gn_ = o0 + wc + j * 16 + cc;
            float wz = wdz[gn_];
#pragma unroll
            for (int i = 0; i < 4; ++i)
#pragma unroll
                for (int rr = 0; rr < 4; ++rr)
                    zp[i][rr] += tanhf(acc[i][j][rr]) * wz;
        }
        // reduce across the 16-lane col group (lanes share rows, differ in cc)
#pragma unroll
        for (int i = 0; i < 4; ++i)
#pragma unroll
            for (int rr = 0; rr < 4; ++rr) {
                float v = zp[i][rr];
                v += __shfl_xor(v, 1);
                v += __shfl_xor(v, 2);
                v += __shfl_xor(v, 4);
                v += __shfl_xor(v, 8);
                if (cc == 0) {
                    int gm_ = t0 + wr + i * 16 + cr + rr;
                    if (gm_ < T) atomicAdd(&zout[gm_], v);
                }
            }
        return;
    }
#pragma unroll
    for (int i = 0; i < 4; ++i) {
#pragma unroll
        for (int j = 0; j < 4; ++j) {
            int gn_ = o0 + wc + j * 16 + cc;
            float bv = bias ? bias[gn_] : 0.f;
#pragma unroll
            for (int rr = 0; rr < 4; ++rr) {
                int gm_ = t0 + wr + i * 16 + cr + rr;
                if (gm_ >= T) continue;
                float v = acc[i][j][rr] + bv;
                if (ACT == 1) v = fmaxf(v, 0.f);
                Cb[(size_t)gm_ * O + gn_] = f2b_rne(v);
            }
        }
    }
}

// ---------------------------------------------------------------- MFMA attention: one wave per (s,h)
__global__ __launch_bounds__(64) void attn_mfma(const unsigned short* __restrict__ qkv,
                                                unsigned short* __restrict__ o) {
    __shared__ __align__(16) unsigned short vt[64 * 40];   // V^T [d][m], stride 40
    __shared__ __align__(16) unsigned short ps[32 * 40];   // P [l][m], stride 40
    int s = blockIdx.x, h = blockIdx.y;
    int lane = threadIdx.x;
    int hd = h * 64;
    int fr = lane & 15, fq = lane >> 4;

    {
        int m = lane >> 1;
        int d0 = (lane & 1) * 32;
        const unsigned short* vrow = qkv + ((size_t)m * S_ + s) * 1536 + 1024 + hd + d0;
        short8 v0 = *(const short8*)(vrow);
        short8 v1 = *(const short8*)(vrow + 8);
        short8 v2 = *(const short8*)(vrow + 16);
        short8 v3 = *(const short8*)(vrow + 24);
#pragma unroll
        for (int j = 0; j < 8; ++j) {
            vt[(d0 + j) * 40 + m]      = (unsigned short)v0[j];
            vt[(d0 + 8 + j) * 40 + m]  = (unsigned short)v1[j];
            vt[(d0 + 16 + j) * 40 + m] = (unsigned short)v2[j];
            vt[(d0 + 24 + j) * 40 + m] = (unsigned short)v3[j];
        }
    }

    floatx4 c[2][2] = {};
#pragma unroll
    for (int ks = 0; ks < 2; ++ks) {
        short8 aq[2], bk[2];
#pragma unroll
        for (int lt = 0; lt < 2; ++lt) {
            int l = lt * 16 + fr;
            aq[lt] = *(const short8*)(qkv + ((size_t)l * S_ + s) * 1536 + hd + ks * 32 + fq * 8);
        }
#pragma unroll
        for (int mt = 0; mt < 2; ++mt) {
            int m = mt * 16 + fr;
            bk[mt] = *(const short8*)(qkv + ((size_t)m * S_ + s) * 1536 + 512 + hd + ks * 32 + fq * 8);
        }
#pragma unroll
        for (int lt = 0; lt < 2; ++lt)
#pragma unroll
            for (int mt = 0; mt < 2; ++mt)
                c[lt][mt] = __builtin_amdgcn_mfma_f32_16x16x32_bf16(aq[lt], bk[mt], c[lt][mt], 0, 0, 0);
    }

#pragma unroll
    for (int lt = 0; lt < 2; ++lt) {
#pragma unroll
        for (int r = 0; r < 4; ++r) {
            float a = c[lt][0][r] * 0.125f;
            float b = c[lt][1][r] * 0.125f;
            float mx = fmaxf(a, b);
#pragma unroll
            for (int off = 1; off < 16; off <<= 1) mx = fmaxf(mx, __shfl_xor(mx, off));
            float ea = expf(a - mx), eb = expf(b - mx);
            float sm = ea + eb;
#pragma unroll
            for (int off = 1; off < 16; off <<= 1) sm += __shfl_xor(sm, off);
            float inv = 1.f / sm;
            int l = lt * 16 + fq * 4 + r;
            ps[l * 40 + fr]      = f2b_rne(ea * inv);
            ps[l * 40 + 16 + fr] = f2b_rne(eb * inv);
        }
    }
    __syncthreads();

    short8 pa[2], vb[4];
#pragma unroll
    for (int lt = 0; lt < 2; ++lt)
        pa[lt] = *(const short8*)&ps[(lt * 16 + fr) * 40 + fq * 8];
#pragma unroll
    for (int dt = 0; dt < 4; ++dt)
        vb[dt] = *(const short8*)&vt[(dt * 16 + fr) * 40 + fq * 8];

    floatx4 oa[2][4] = {};
#pragma unroll
    for (int lt = 0; lt < 2; ++lt)
#pragma unroll
        for (int dt = 0; dt < 4; ++dt)
            oa[lt][dt] = __builtin_amdgcn_mfma_f32_16x16x32_bf16(pa[lt], vb[dt], oa[lt][dt], 0, 0, 0);

#pragma unroll
    for (int lt = 0; lt < 2; ++lt)
#pragma unroll
        for (int dt = 0; dt < 4; ++dt)
#pragma unroll
            for (int r = 0; r < 4; ++r) {
                int l = lt * 16 + fq * 4 + r;
                o[((size_t)l * S_ + s) * E_ + hd + dt * 16 + fr] = f2b_rne(oa[lt][dt][r]);
            }
}

// ---------------------------------------------------------------- x = LN(x + h); wave-per-token (64 lanes x 8 elems)
// WX=false skips the f32 x write (dead after the last LN - only xb is read later).
template <bool WX>
__global__ __launch_bounds__(256) void add_ln(float* __restrict__ x,
                                              unsigned short* __restrict__ xb,
                                              const unsigned short* __restrict__ h,
                                              const float* __restrict__ w,
                                              const float* __restrict__ b) {
    int t = (blockIdx.x << 2) + (threadIdx.x >> 6);   // token (grid = T_/4 blocks)
    int lane = threadIdx.x & 63;
    int i0 = lane * 8;
    float* xr = x + (size_t)t * E_;
    const unsigned short* hr = h + (size_t)t * E_;
    float4 xv0 = *(const float4*)&xr[i0];
    float4 xv1 = *(const float4*)&xr[i0 + 4];
    short8 hv = *(const short8*)&hr[i0];
    float v[8];
    v[0] = xv0.x + bf2f((unsigned short)hv[0]);
    v[1] = xv0.y + bf2f((unsigned short)hv[1]);
    v[2] = xv0.z + bf2f((unsigned short)hv[2]);
    v[3] = xv0.w + bf2f((unsigned short)hv[3]);
    v[4] = xv1.x + bf2f((unsigned short)hv[4]);
    v[5] = xv1.y + bf2f((unsigned short)hv[5]);
    v[6] = xv1.z + bf2f((unsigned short)hv[6]);
    v[7] = xv1.w + bf2f((unsigned short)hv[7]);

    float sum = 0.f;
#pragma unroll
    for (int j = 0; j < 8; ++j) sum += v[j];
#pragma unroll
    for (int off = 32; off; off >>= 1) sum += __shfl_xor(sum, off);
    float mu = sum * (1.0f / E_);

    float qs = 0.f;
#pragma unroll
    for (int j = 0; j < 8; ++j) { float d = v[j] - mu; qs += d * d; }
#pragma unroll
    for (int off = 32; off; off >>= 1) qs += __shfl_xor(qs, off);
    float rstd = rsqrtf(qs * (1.0f / E_) + 1e-5f);

    float4 wv0 = *(const float4*)&w[i0];
    float4 wv1 = *(const float4*)&w[i0 + 4];
    float4 bv0 = *(const float4*)&b[i0];
    float4 bv1 = *(const float4*)&b[i0 + 4];
    float o[8];
    o[0] = (v[0] - mu) * rstd * wv0.x + bv0.x;
    o[1] = (v[1] - mu) * rstd * wv0.y + bv0.y;
    o[2] = (v[2] - mu) * rstd * wv0.z + bv0.z;
    o[3] = (v[3] - mu) * rstd * wv0.w + bv0.w;
    o[4] = (v[4] - mu) * rstd * wv1.x + bv1.x;
    o[5] = (v[5] - mu) * rstd * wv1.y + bv1.y;
    o[6] = (v[6] - mu) * rstd * wv1.z + bv1.z;
    o[7] = (v[7] - mu) * rstd * wv1.w + bv1.w;
    if (WX) {
        *(float4*)&xr[i0]     = make_float4(o[0], o[1], o[2], o[3]);
        *(float4*)&xr[i0 + 4] = make_float4(o[4], o[5], o[6], o[7]);
    }
    short8 ob;
#pragma unroll
    for (int j = 0; j < 8; ++j) ob[j] = (short)f2b_rne(o[j]);
    *(short8*)&xb[(size_t)t * E_ + i0] = ob;
}

// ---------------------------------------------------------------- discriminator + sigmoid, wave-per-token
__global__ __launch_bounds__(256) void disc_kernel(const float* __restrict__ bert,
                                                   const float* __restrict__ z,
                                                   const float* __restrict__ wd,
                                                   const float* __restrict__ bd,
                                                   float* __restrict__ out) {
    int t = (blockIdx.x << 2) + (threadIdx.x >> 6);   // grid = T_/4 blocks
    int lane = threadIdx.x & 63;
    int i0 = lane * 12;                               // 64 * 12 = 768
    const float* br = bert + (size_t)t * F_ + i0;
    const float* wr = wd + i0;
    float s = 0.f;
#pragma unroll
    for (int j = 0; j < 12; j += 4) {
        float4 bv = *(const float4*)(br + j);
        float4 wv = *(const float4*)(wr + j);
        s += bv.x * wv.x + bv.y * wv.y + bv.z * wv.z + bv.w * wv.w;
    }
#pragma unroll
    for (int off = 32; off; off >>= 1) s += __shfl_xor(s, off);
    if (lane == 0) {
        float zz = s + z[t] + bd[0];
        out[t] = 1.f / (1.f + expf(-zz));
    }
}

// ---------------------------------------------------------------- launch
extern "C" void kernel_launch(void* const* d_in, const int* in_sizes, int n_in,
                              void* d_out, int out_size, void* d_ws, size_t ws_size,
                              hipStream_t stream) {
    const int*   pos1 = (const int*)d_in[0];
    const int*   pos2 = (const int*)d_in[1];
    const float* bert = (const float*)d_in[2];
    const float* fb   = (const float*)d_in[3];
    const float* emb  = (const float*)d_in[4];
    const float* wi   = (const float*)d_in[5];
    const float* bi   = (const float*)d_in[6];
    const float* wo   = (const float*)d_in[7];
    const float* bo   = (const float*)d_in[8];
    const float* ln1w = (const float*)d_in[9];
    const float* ln1b = (const float*)d_in[10];
    const float* ln2w = (const float*)d_in[11];
    const float* ln2b = (const float*)d_in[12];
    const float* w1   = (const float*)d_in[13];
    const float* b1   = (const float*)d_in[14];
    const float* w2   = (const float*)d_in[15];
    const float* b2   = (const float*)d_in[16];
    const float* wm   = (const float*)d_in[17];
    const float* wd   = (const float*)d_in[18];
    const float* bd   = (const float*)d_in[19];
    float* out = (float*)d_out;

    // workspace layout
    float* ws   = (float*)d_ws;
    int*   span = (int*)ws;                                   // 16384 i
    float* x    = ws + 16384;                                 // T_*512 f
    unsigned short* xb  = (unsigned short*)(x + (size_t)T_ * 512);   // TP_*512 bf16
    unsigned short* atb = xb + (size_t)TP_ * 512;                    // TP_*512 bf16
    unsigned short* hb  = atb + (size_t)TP_ * 512;                   // T_*512 bf16
    unsigned short* U   = hb + (size_t)T_ * 512;              // union: qkv | h1
    unsigned short* qkvb = U;
    unsigned short* h1b  = U;
    unsigned short* wib  = U + (size_t)TP_ * 2048;            // weights bf16, contiguous
    const int NWI = 2 * 1536 * 512;
    const int NWO = 2 * 512 * 512;
    const int NW1 = 2 * 2048 * 512;
    const int NW2 = 2 * 512 * 2048;
    const int NWM = 768 * 512;
    unsigned short* wob = wib + NWI;
    unsigned short* w1b = wob + NWO;
    unsigned short* w2b = w1b + NW1;
    unsigned short* wmb = w2b + NW2;
    // z (T_ f32) aliases atb: atb is dead after the layer-2 WO GEMM reads it.
    float* z = (float*)atb;

    span_kernel<<<B_, 256, 0, stream>>>(pos1, span);
    {
        int c0 = NWI, c1 = c0 + NWO, c2 = c1 + NW1, c3 = c2 + NW2, c4 = c3 + NWM;
        f2b5_kernel<<<(c4 / 4 + 255) / 256, 256, 0, stream>>>(wi, wo, w1, w2, wm, wib,
                                                              c0, c1, c2, c3, c4);
    }
    build_x<<<T_ / 4, 256, 0, stream>>>(emb, pos2, fb, span, x, xb);

    for (int l = 0; l < 2; ++l) {
        gemm_bf16<0, 512><<<GMT_ * (1536 / 128), 256, 0, stream>>>(
            xb, wib + (size_t)l * 1536 * 512, bi + l * 1536, qkvb, T_, 1536, nullptr, nullptr);
        attn_mfma<<<dim3(S_, NH_), 64, 0, stream>>>(qkvb, atb);
        gemm_bf16<0, 512><<<GMT_ * (512 / 128), 256, 0, stream>>>(
            atb, wob + (size_t)l * 512 * 512, bo + l * 512, hb, T_, 512, nullptr, nullptr);
        add_ln<true><<<T_ / 4, 256, 0, stream>>>(x, xb, hb, ln1w + l * 512, ln1b + l * 512);
        gemm_bf16<1, 512><<<GMT_ * (2048 / 128), 256, 0, stream>>>(
            xb, w1b + (size_t)l * 2048 * 512, b1 + l * 2048, h1b, T_, 2048, nullptr, nullptr);
        gemm_bf16<0, 2048><<<GMT_ * (512 / 128), 256, 0, stream>>>(
            h1b, w2b + (size_t)l * 512 * 2048, b2 + l * 512, hb, T_, 512, nullptr, nullptr);
        if (l == 0)
            add_ln<true><<<T_ / 4, 256, 0, stream>>>(x, xb, hb, ln2w + l * 512, ln2b + l * 512);
        else
            add_ln<false><<<T_ / 4, 256, 0, stream>>>(x, xb, hb, ln2w + l * 512, ln2b + l * 512);
    }
    // atb now dead -> reuse as z accumulator for the fused final GEMM + disc dot
    hipMemsetAsync(z, 0, (size_t)T_ * sizeof(float), stream);
    gemm_bf16<2, 512><<<GMT_ * (768 / 128), 256, 0, stream>>>(
        xb, wmb, nullptr, nullptr, T_, 768, wd + F_, z);
    disc_kernel<<<T_ / 4, 256, 0, stream>>>(bert, z, wd, bd, out);
}

// Round 11
// 710.448 us; speedup vs baseline: 1.4080x; 1.0260x over previous
//
#include <hip/hip_runtime.h>
#include <hip/hip_bf16.h>

#define B_   32
#define M_   512
#define E_   512
#define S_   513            // M+1
#define T_   (B_ * S_)      // 16416 tokens
#define TP_  16512          // 129*128 padded
#define NH_  8
#define DH_  64
#define F_   768
#define DFF_ 2048

#define GMT_ 129            // m tiles

typedef short short8 __attribute__((ext_vector_type(8)));
typedef float floatx4 __attribute__((ext_vector_type(4)));

__device__ __forceinline__ float bf2f(unsigned short u) {
    return __uint_as_float(((unsigned int)u) << 16);
}
__device__ __forceinline__ unsigned short f2b_rne(float f) {
    unsigned int u = __float_as_uint(f);
    unsigned int r = u + 0x7FFF + ((u >> 16) & 1);
    return (unsigned short)(r >> 16);
}
__device__ __forceinline__ void gload16(const void* g, void* l) {
    __builtin_amdgcn_global_load_lds(
        (const __attribute__((address_space(1))) void*)g,
        (__attribute__((address_space(3))) void*)l, 16, 0, 0);
}
// fast tanh via hardware exp: exact at +/-inf, ~1e-6 rel error
__device__ __forceinline__ float tanh_fast(float x) {
    return 1.f - 2.f / (__expf(2.f * x) + 1.f);
}

// ---------------------------------------------------------------- span ids + f32->bf16 weight convert, fused
// blocks [0, B_): span computation; blocks [B_, ...): x4-vectorized 5-segment convert
__global__ void span_f2b5_kernel(const int* __restrict__ pos1, int* __restrict__ span,
                                 const float* __restrict__ s0, const float* __restrict__ s1,
                                 const float* __restrict__ s2, const float* __restrict__ s3,
                                 const float* __restrict__ s4,
                                 unsigned short* __restrict__ dst,
                                 int c0, int c1, int c2, int c3, int c4) {
    int tid = threadIdx.x;
    if (blockIdx.x >= B_) {
        int i = ((blockIdx.x - B_) * 256 + tid) * 4;
        if (i >= c4) return;
        const float* src;
        if      (i < c0) src = s0 + i;
        else if (i < c1) src = s1 + (i - c0);
        else if (i < c2) src = s2 + (i - c1);
        else if (i < c3) src = s3 + (i - c2);
        else             src = s4 + (i - c3);
        float4 v = *(const float4*)src;
        ushort4 o;
        o.x = f2b_rne(v.x); o.y = f2b_rne(v.y); o.z = f2b_rne(v.z); o.w = f2b_rne(v.w);
        *(ushort4*)&dst[i] = o;
        return;
    }
    int b = blockIdx.x;
    __shared__ int st[M_], en[M_];
    __shared__ int redm[4];
    for (int j = tid; j < M_; j += 256) {
        st[j] = pos1[(b * M_ + j) * 2];
        en[j] = pos1[(b * M_ + j) * 2 + 1];
    }
    __syncthreads();
    // parallel first-zero: min index j with en[j]==0 (prefix-validity semantics)
    int idx = M_;
    for (int j = tid; j < M_; j += 256)
        if (en[j] == 0 && j < idx) idx = j;
    for (int off = 32; off; off >>= 1) idx = min(idx, __shfl_down(idx, off));
    if ((tid & 63) == 0) redm[tid >> 6] = idx;
    __syncthreads();
    int n = min(min(redm[0], redm[1]), min(redm[2], redm[3]));
    for (int k = tid; k < M_; k += 256) {
        int best = -1;
        for (int j = 0; j < n; ++j)
            if (st[j] <= k && k < en[j]) best = j;
        span[b * M_ + k] = best;
    }
}

// ---------------------------------------------------------------- build x0 (f32 + bf16 shadow), PE inline
__global__ __launch_bounds__(256) void build_x(const float* __restrict__ emb,
                        const int* __restrict__ pos2,
                        const float* __restrict__ fbase,
                        const int* __restrict__ span,
                        float* __restrict__ x,
                        unsigned short* __restrict__ xb) {
    int gid = blockIdx.x * 256 + threadIdx.x;      // 0 .. T_*64-1
    int t  = gid >> 6;                              // token
    int e0 = (gid & 63) * 8;                        // first of 8 elems
    int s = t % S_;
    int b = t / S_;
    float v[8];
    if (s == 0) {
        float4 a = *(const float4*)&emb[E_ + e0];
        float4 c = *(const float4*)&emb[E_ + e0 + 4];
        v[0]=a.x; v[1]=a.y; v[2]=a.z; v[3]=a.w; v[4]=c.x; v[5]=c.y; v[6]=c.z; v[7]=c.w;
    } else {
        int k = s - 1;
        int sid = span[b * M_ + k];
        if (sid >= 0) {
            int p = pos2[b * M_ + sid];
            const float* er = emb + (size_t)p * E_ + e0;
            float4 a = *(const float4*)er;
            float4 c = *(const float4*)(er + 4);
            v[0]=a.x; v[1]=a.y; v[2]=a.z; v[3]=a.w; v[4]=c.x; v[5]=c.y; v[6]=c.z; v[7]=c.w;
            float fs = (float)sid;
#pragma unroll
            for (int jj = 0; jj < 4; ++jj) {
                float ex = (float)(e0 + 2 * jj) * (1.0f / 512.0f);
                float ang = fs * exp2f(-ex * 13.287712379549449f);   // log2(10000)
                float sn, cs;
                __sincosf(ang, &sn, &cs);
                v[2 * jj]     += sn;
                v[2 * jj + 1] += cs;
            }
        } else {
            const float* fr = fbase + ((size_t)b * M_ + k) * E_ + e0;
            float4 a = *(const float4*)fr;
            float4 c = *(const float4*)(fr + 4);
            v[0]=a.x; v[1]=a.y; v[2]=a.z; v[3]=a.w; v[4]=c.x; v[5]=c.y; v[6]=c.z; v[7]=c.w;
        }
    }
    size_t o = (size_t)t * E_ + e0;
    *(float4*)&x[o]     = make_float4(v[0], v[1], v[2], v[3]);
    *(float4*)&x[o + 4] = make_float4(v[4], v[5], v[6], v[7]);
    short8 ob;
#pragma unroll
    for (int j = 0; j < 8; ++j) ob[j] = (short)f2b_rne(v[j]);
    *(short8*)&xb[o] = ob;
}

// ---------------------------------------------------------------- bf16 MFMA GEMM (NT)
// R8-verified body (best measured: FFN1-class 71.6 us, zero bank conflicts):
// 3 LDS buffers, counted s_waitcnt vmcnt(4) (stage(t+1) stays in flight across
// the barrier; vmcnt(0) only at the last peeled step), chunk-XOR swizzle on BOTH
// sides (pre-swizzled per-lane global source for the linear global_load_lds dest
// + same XOR on ds_read), setprio(1) around the MFMA cluster.
// FIVE falsified departures this session (R3 tile, R4 8-phase, R5 no-LDS, R9
// A-from-global, plus R1-vs-R0 schedule neutral) - do not restructure further.
// ACT==2 fuses the discriminator pos-feature dot (no C store).
template <int ACT, int KT>  // ACT: 0 none 1 relu 2 tanh+zdot(no C write)
__global__ __launch_bounds__(256, 3) void gemm_bf16(const unsigned short* __restrict__ A,
                                                    const unsigned short* __restrict__ W,
                                                    const float* __restrict__ bias,
                                                    unsigned short* __restrict__ Cb,
                                                    int T, int O,
                                                    const float* __restrict__ wdz,
                                                    float* __restrict__ zout) {
    constexpr int K = KT;
    constexpr int NSTEP = K / 32;
    __shared__ __align__(16) unsigned short sA[3][128 * 32];
    __shared__ __align__(16) unsigned short sB[3][128 * 32];
    int tid = threadIdx.x;
    int lane = tid & 63, wv = tid >> 6;
    int wr = (wv >> 1) * 64, wc = (wv & 1) * 64;

    // ---- panel swizzle: 8 m-tiles per panel, n fastest within panel
    int gn = O / 128;
    int per_panel = 8 * gn;
    int id = blockIdx.x;
    int p = id / per_panel;
    int r = id - p * per_panel;
    int mrem = GMT_ - p * 8; if (mrem > 8) mrem = 8;
    int mt = p * 8 + r % mrem;
    int nt = r / mrem;
    int t0 = mt * 128, o0 = nt * 128;

    floatx4 acc[4][4] = {};

    // staging: lane covers row (lane>>2), chunk (lane&3); global chunk pre-swizzled
    // with s(row) = (row>>1)&3 == (lane>>3)&3 (same for row+16).
    int swz_st = (((lane & 3) ^ ((lane >> 3) & 3))) * 8;
    const unsigned short* Ag = A + (size_t)(t0 + wv * 32 + (lane >> 2)) * K + swz_st;
    const unsigned short* Bg = W + (size_t)(o0 + wv * 32 + (lane >> 2)) * K + swz_st;
    const size_t row16 = (size_t)16 * K;
    const int wvo = wv * 1024;

    // fragment read: row = (wr|wc) + i*16 + fr; chunk = fq ^ ((fr>>1)&3)
    int fr = lane & 15;
    int fks = (((lane >> 4) ^ ((lane >> 1) & 3))) * 8;

    auto stage = [&](unsigned short* da, unsigned short* db, int k) {
        gload16(Ag + k, da + wvo);
        gload16(Ag + row16 + k, da + wvo + 512);
        gload16(Bg + k, db + wvo);
        gload16(Bg + row16 + k, db + wvo + 512);
    };
    auto compute = [&](const unsigned short* ca, const unsigned short* cb) {
        short8 af[4], bfr[4];
#pragma unroll
        for (int i = 0; i < 4; ++i)
            af[i] = *(const short8*)&ca[(wr + i * 16 + fr) * 32 + fks];
#pragma unroll
        for (int j = 0; j < 4; ++j)
            bfr[j] = *(const short8*)&cb[(wc + j * 16 + fr) * 32 + fks];
        __builtin_amdgcn_s_setprio(1);
#pragma unroll
        for (int i = 0; i < 4; ++i)
#pragma unroll
            for (int j = 0; j < 4; ++j)
                acc[i][j] = __builtin_amdgcn_mfma_f32_16x16x32_bf16(af[i], bfr[j], acc[i][j], 0, 0, 0);
        __builtin_amdgcn_s_setprio(0);
    };

    unsigned short *a0 = sA[0], *a1 = sA[1], *a2 = sA[2];
    unsigned short *b0 = sB[0], *b1 = sB[1], *b2 = sB[2];

    // prologue: 2 stages in flight (8 vm ops/wave)
    stage(a0, b0, 0);
    stage(a1, b1, 32);

#pragma unroll 3
    for (int t = 0; t < NSTEP - 2; ++t) {
        // wait stage(t) only; stage(t+1)'s 4 loads stay in flight across the barrier
        asm volatile("s_waitcnt vmcnt(4)" ::: "memory");
        __builtin_amdgcn_s_barrier();
        asm volatile("" ::: "memory");
        stage(a2, b2, (t + 2) * 32);   // overwrites slot (t-1)%3: all reads of it done pre-barrier
        compute(a0, b0);
        unsigned short* ta = a0; a0 = a1; a1 = a2; a2 = ta;
        unsigned short* tb = b0; b0 = b1; b1 = b2; b2 = tb;
    }
    // t = NSTEP-2: stage(NSTEP-1) may still be in flight
    asm volatile("s_waitcnt vmcnt(4)" ::: "memory");
    __builtin_amdgcn_s_barrier();
    asm volatile("" ::: "memory");
    compute(a0, b0);
    a0 = a1; b0 = b1;
    // t = NSTEP-1: full drain (only place vmcnt reaches 0)
    asm volatile("s_waitcnt vmcnt(0)" ::: "memory");
    __builtin_amdgcn_s_barrier();
    asm volatile("" ::: "memory");
    compute(a0, b0);

    int cr = (lane >> 4) * 4;
    int cc = lane & 15;
    if (ACT == 2) {
        // fused tanh + z-dot epilogue: zp[i][rr] = sum_j tanh(acc) * wdz[col]
        float zp[4][4];
#pragma unroll
        for (int i = 0; i < 4; ++i)
#pragma unroll
            for (int rr = 0; rr < 4; ++rr) zp[i][rr] = 0.f;
#pragma unroll
        for (int j = 0; j < 4; ++j) {
            int gn_ = o0 + wc + j * 16 + cc;
            float wz = wdz[gn_];
#pragma unroll
            for (int i = 0; i < 4; ++i)
#pragma unroll
                for (int rr = 0; rr < 4; ++rr)
                    zp[i][rr] += tanh_fast(acc[i][j][rr]) * wz;
        }
        // reduce across the 16-lane col group (lanes share rows, differ in cc)
#pragma unroll
        for (int i = 0; i < 4; ++i)
#pragma unroll
            for (int rr = 0; rr < 4; ++rr) {
                float v = zp[i][rr];
                v += __shfl_xor(v, 1);
                v += __shfl_xor(v, 2);
                v += __shfl_xor(v, 4);
                v += __shfl_xor(v, 8);
                if (cc == 0) {
                    int gm_ = t0 + wr + i * 16 + cr + rr;
                    if (gm_ < T) atomicAdd(&zout[gm_], v);
                }
            }
        return;
    }
#pragma unroll
    for (int i = 0; i < 4; ++i) {
#pragma unroll
        for (int j = 0; j < 4; ++j) {
            int gn_ = o0 + wc + j * 16 + cc;
            float bv = bias ? bias[gn_] : 0.f;
#pragma unroll
            for (int rr = 0; rr < 4; ++rr) {
                int gm_ = t0 + wr + i * 16 + cr + rr;
                if (gm_ >= T) continue;
                float v = acc[i][j][rr] + bv;
                if (ACT == 1) v = fmaxf(v, 0.f);
                Cb[(size_t)gm_ * O + gn_] = f2b_rne(v);
            }
        }
    }
}

// ---------------------------------------------------------------- MFMA attention: one wave per (s,h)
__global__ __launch_bounds__(64) void attn_mfma(const unsigned short* __restrict__ qkv,
                                                unsigned short* __restrict__ o) {
    __shared__ __align__(16) unsigned short vt[64 * 40];   // V^T [d][m], stride 40
    __shared__ __align__(16) unsigned short ps[32 * 40];   // P [l][m], stride 40
    int s = blockIdx.x, h = blockIdx.y;
    int lane = threadIdx.x;
    int hd = h * 64;
    int fr = lane & 15, fq = lane >> 4;

    {
        int m = lane >> 1;
        int d0 = (lane & 1) * 32;
        const unsigned short* vrow = qkv + ((size_t)m * S_ + s) * 1536 + 1024 + hd + d0;
        short8 v0 = *(const short8*)(vrow);
        short8 v1 = *(const short8*)(vrow + 8);
        short8 v2 = *(const short8*)(vrow + 16);
        short8 v3 = *(const short8*)(vrow + 24);
#pragma unroll
        for (int j = 0; j < 8; ++j) {
            vt[(d0 + j) * 40 + m]      = (unsigned short)v0[j];
            vt[(d0 + 8 + j) * 40 + m]  = (unsigned short)v1[j];
            vt[(d0 + 16 + j) * 40 + m] = (unsigned short)v2[j];
            vt[(d0 + 24 + j) * 40 + m] = (unsigned short)v3[j];
        }
    }

    floatx4 c[2][2] = {};
#pragma unroll
    for (int ks = 0; ks < 2; ++ks) {
        short8 aq[2], bk[2];
#pragma unroll
        for (int lt = 0; lt < 2; ++lt) {
            int l = lt * 16 + fr;
            aq[lt] = *(const short8*)(qkv + ((size_t)l * S_ + s) * 1536 + hd + ks * 32 + fq * 8);
        }
#pragma unroll
        for (int mt = 0; mt < 2; ++mt) {
            int m = mt * 16 + fr;
            bk[mt] = *(const short8*)(qkv + ((size_t)m * S_ + s) * 1536 + 512 + hd + ks * 32 + fq * 8);
        }
#pragma unroll
        for (int lt = 0; lt < 2; ++lt)
#pragma unroll
            for (int mt = 0; mt < 2; ++mt)
                c[lt][mt] = __builtin_amdgcn_mfma_f32_16x16x32_bf16(aq[lt], bk[mt], c[lt][mt], 0, 0, 0);
    }

#pragma unroll
    for (int lt = 0; lt < 2; ++lt) {
#pragma unroll
        for (int r = 0; r < 4; ++r) {
            float a = c[lt][0][r] * 0.125f;
            float b = c[lt][1][r] * 0.125f;
            float mx = fmaxf(a, b);
#pragma unroll
            for (int off = 1; off < 16; off <<= 1) mx = fmaxf(mx, __shfl_xor(mx, off));
            float ea = __expf(a - mx), eb = __expf(b - mx);
            float sm = ea + eb;
#pragma unroll
            for (int off = 1; off < 16; off <<= 1) sm += __shfl_xor(sm, off);
            float inv = 1.f / sm;
            int l = lt * 16 + fq * 4 + r;
            ps[l * 40 + fr]      = f2b_rne(ea * inv);
            ps[l * 40 + 16 + fr] = f2b_rne(eb * inv);
        }
    }
    __syncthreads();

    short8 pa[2], vb[4];
#pragma unroll
    for (int lt = 0; lt < 2; ++lt)
        pa[lt] = *(const short8*)&ps[(lt * 16 + fr) * 40 + fq * 8];
#pragma unroll
    for (int dt = 0; dt < 4; ++dt)
        vb[dt] = *(const short8*)&vt[(dt * 16 + fr) * 40 + fq * 8];

    floatx4 oa[2][4] = {};
#pragma unroll
    for (int lt = 0; lt < 2; ++lt)
#pragma unroll
        for (int dt = 0; dt < 4; ++dt)
            oa[lt][dt] = __builtin_amdgcn_mfma_f32_16x16x32_bf16(pa[lt], vb[dt], oa[lt][dt], 0, 0, 0);

#pragma unroll
    for (int lt = 0; lt < 2; ++lt)
#pragma unroll
        for (int dt = 0; dt < 4; ++dt)
#pragma unroll
            for (int r = 0; r < 4; ++r) {
                int l = lt * 16 + fq * 4 + r;
                o[((size_t)l * S_ + s) * E_ + hd + dt * 16 + fr] = f2b_rne(oa[lt][dt][r]);
            }
}

// ---------------------------------------------------------------- x = LN(x + h); wave-per-token (64 lanes x 8 elems)
// WX=false skips the f32 x write (dead after the last LN - only xb is read later).
template <bool WX>
__global__ __launch_bounds__(256) void add_ln(float* __restrict__ x,
                                              unsigned short* __restrict__ xb,
                                              const unsigned short* __restrict__ h,
                                              const float* __restrict__ w,
                                              const float* __restrict__ b) {
    int t = (blockIdx.x << 2) + (threadIdx.x >> 6);   // token (grid = T_/4 blocks)
    int lane = threadIdx.x & 63;
    int i0 = lane * 8;
    float* xr = x + (size_t)t * E_;
    const unsigned short* hr = h + (size_t)t * E_;
    float4 xv0 = *(const float4*)&xr[i0];
    float4 xv1 = *(const float4*)&xr[i0 + 4];
    short8 hv = *(const short8*)&hr[i0];
    float v[8];
    v[0] = xv0.x + bf2f((unsigned short)hv[0]);
    v[1] = xv0.y + bf2f((unsigned short)hv[1]);
    v[2] = xv0.z + bf2f((unsigned short)hv[2]);
    v[3] = xv0.w + bf2f((unsigned short)hv[3]);
    v[4] = xv1.x + bf2f((unsigned short)hv[4]);
    v[5] = xv1.y + bf2f((unsigned short)hv[5]);
    v[6] = xv1.z + bf2f((unsigned short)hv[6]);
    v[7] = xv1.w + bf2f((unsigned short)hv[7]);

    float sum = 0.f;
#pragma unroll
    for (int j = 0; j < 8; ++j) sum += v[j];
#pragma unroll
    for (int off = 32; off; off >>= 1) sum += __shfl_xor(sum, off);
    float mu = sum * (1.0f / E_);

    float qs = 0.f;
#pragma unroll
    for (int j = 0; j < 8; ++j) { float d = v[j] - mu; qs += d * d; }
#pragma unroll
    for (int off = 32; off; off >>= 1) qs += __shfl_xor(qs, off);
    float rstd = rsqrtf(qs * (1.0f / E_) + 1e-5f);

    float4 wv0 = *(const float4*)&w[i0];
    float4 wv1 = *(const float4*)&w[i0 + 4];
    float4 bv0 = *(const float4*)&b[i0];
    float4 bv1 = *(const float4*)&b[i0 + 4];
    float o[8];
    o[0] = (v[0] - mu) * rstd * wv0.x + bv0.x;
    o[1] = (v[1] - mu) * rstd * wv0.y + bv0.y;
    o[2] = (v[2] - mu) * rstd * wv0.z + bv0.z;
    o[3] = (v[3] - mu) * rstd * wv0.w + bv0.w;
    o[4] = (v[4] - mu) * rstd * wv1.x + bv1.x;
    o[5] = (v[5] - mu) * rstd * wv1.y + bv1.y;
    o[6] = (v[6] - mu) * rstd * wv1.z + bv1.z;
    o[7] = (v[7] - mu) * rstd * wv1.w + bv1.w;
    if (WX) {
        *(float4*)&xr[i0]     = make_float4(o[0], o[1], o[2], o[3]);
        *(float4*)&xr[i0 + 4] = make_float4(o[4], o[5], o[6], o[7]);
    }
    short8 ob;
#pragma unroll
    for (int j = 0; j < 8; ++j) ob[j] = (short)f2b_rne(o[j]);
    *(short8*)&xb[(size_t)t * E_ + i0] = ob;
}

// ---------------------------------------------------------------- discriminator + sigmoid, wave-per-token
__global__ __launch_bounds__(256) void disc_kernel(const float* __restrict__ bert,
                                                   const float* __restrict__ z,
                                                   const float* __restrict__ wd,
                                                   const float* __restrict__ bd,
                                                   float* __restrict__ out) {
    int t = (blockIdx.x << 2) + (threadIdx.x >> 6);   // grid = T_/4 blocks
    int lane = threadIdx.x & 63;
    int i0 = lane * 12;                               // 64 * 12 = 768
    const float* br = bert + (size_t)t * F_ + i0;
    const float* wr = wd + i0;
    float s = 0.f;
#pragma unroll
    for (int j = 0; j < 12; j += 4) {
        float4 bv = *(const float4*)(br + j);
        float4 wv = *(const float4*)(wr + j);
        s += bv.x * wv.x + bv.y * wv.y + bv.z * wv.z + bv.w * wv.w;
    }
#pragma unroll
    for (int off = 32; off; off >>= 1) s += __shfl_xor(s, off);
    if (lane == 0) {
        float zz = s + z[t] + bd[0];
        out[t] = 1.f / (1.f + __expf(-zz));
    }
}

// ---------------------------------------------------------------- launch
extern "C" void kernel_launch(void* const* d_in, const int* in_sizes, int n_in,
                              void* d_out, int out_size, void* d_ws, size_t ws_size,
                              hipStream_t stream) {
    const int*   pos1 = (const int*)d_in[0];
    const int*   pos2 = (const int*)d_in[1];
    const float* bert = (const float*)d_in[2];
    const float* fb   = (const float*)d_in[3];
    const float* emb  = (const float*)d_in[4];
    const float* wi   = (const float*)d_in[5];
    const float* bi   = (const float*)d_in[6];
    const float* wo   = (const float*)d_in[7];
    const float* bo   = (const float*)d_in[8];
    const float* ln1w = (const float*)d_in[9];
    const float* ln1b = (const float*)d_in[10];
    const float* ln2w = (const float*)d_in[11];
    const float* ln2b = (const float*)d_in[12];
    const float* w1   = (const float*)d_in[13];
    const float* b1   = (const float*)d_in[14];
    const float* w2   = (const float*)d_in[15];
    const float* b2   = (const float*)d_in[16];
    const float* wm   = (const float*)d_in[17];
    const float* wd   = (const float*)d_in[18];
    const float* bd   = (const float*)d_in[19];
    float* out = (float*)d_out;

    // workspace layout
    float* ws   = (float*)d_ws;
    int*   span = (int*)ws;                                   // 16384 i
    float* x    = ws + 16384;                                 // T_*512 f
    unsigned short* xb  = (unsigned short*)(x + (size_t)T_ * 512);   // TP_*512 bf16
    unsigned short* atb = xb + (size_t)TP_ * 512;                    // TP_*512 bf16
    unsigned short* hb  = atb + (size_t)TP_ * 512;                   // T_*512 bf16
    unsigned short* U   = hb + (size_t)T_ * 512;              // union: qkv | h1
    unsigned short* qkvb = U;
    unsigned short* h1b  = U;
    unsigned short* wib  = U + (size_t)TP_ * 2048;            // weights bf16, contiguous
    const int NWI = 2 * 1536 * 512;
    const int NWO = 2 * 512 * 512;
    const int NW1 = 2 * 2048 * 512;
    const int NW2 = 2 * 512 * 2048;
    const int NWM = 768 * 512;
    unsigned short* wob = wib + NWI;
    unsigned short* w1b = wob + NWO;
    unsigned short* w2b = w1b + NW1;
    unsigned short* wmb = w2b + NW2;
    // z (T_ f32) aliases atb: atb is dead after the layer-2 WO GEMM reads it.
    float* z = (float*)atb;

    {
        int c0 = NWI, c1 = c0 + NWO, c2 = c1 + NW1, c3 = c2 + NW2, c4 = c3 + NWM;
        int nf = (c4 / 4 + 255) / 256;
        span_f2b5_kernel<<<B_ + nf, 256, 0, stream>>>(pos1, span, wi, wo, w1, w2, wm, wib,
                                                      c0, c1, c2, c3, c4);
    }
    build_x<<<T_ / 4, 256, 0, stream>>>(emb, pos2, fb, span, x, xb);

    for (int l = 0; l < 2; ++l) {
        gemm_bf16<0, 512><<<GMT_ * (1536 / 128), 256, 0, stream>>>(
            xb, wib + (size_t)l * 1536 * 512, bi + l * 1536, qkvb, T_, 1536, nullptr, nullptr);
        attn_mfma<<<dim3(S_, NH_), 64, 0, stream>>>(qkvb, atb);
        gemm_bf16<0, 512><<<GMT_ * (512 / 128), 256, 0, stream>>>(
            atb, wob + (size_t)l * 512 * 512, bo + l * 512, hb, T_, 512, nullptr, nullptr);
        add_ln<true><<<T_ / 4, 256, 0, stream>>>(x, xb, hb, ln1w + l * 512, ln1b + l * 512);
        gemm_bf16<1, 512><<<GMT_ * (2048 / 128), 256, 0, stream>>>(
            xb, w1b + (size_t)l * 2048 * 512, b1 + l * 2048, h1b, T_, 2048, nullptr, nullptr);
        gemm_bf16<0, 2048><<<GMT_ * (512 / 128), 256, 0, stream>>>(
            h1b, w2b + (size_t)l * 512 * 2048, b2 + l * 512, hb, T_, 512, nullptr, nullptr);
        if (l == 0)
            add_ln<true><<<T_ / 4, 256, 0, stream>>>(x, xb, hb, ln2w + l * 512, ln2b + l * 512);
        else
            add_ln<false><<<T_ / 4, 256, 0, stream>>>(x, xb, hb, ln2w + l * 512, ln2b + l * 512);
    }
    // atb now dead -> reuse as z accumulator for the fused final GEMM + disc dot
    hipMemsetAsync(z, 0, (size_t)T_ * sizeof(float), stream);
    gemm_bf16<2, 512><<<GMT_ * (768 / 128), 256, 0, stream>>>(
        xb, wmb, nullptr, nullptr, T_, 768, wd + F_, z);
    disc_kernel<<<T_ / 4, 256, 0, stream>>>(bert, z, wd, bd, out);
}

// Round 12
// 707.399 us; speedup vs baseline: 1.4141x; 1.0043x over previous
//
#include <hip/hip_runtime.h>
#include <hip/hip_bf16.h>

#define B_   32
#define M_   512
#define E_   512
#define S_   513            // M+1
#define T_   (B_ * S_)      // 16416 tokens
#define TP_  16512          // 129*128 padded
#define NH_  8
#define DH_  64
#define F_   768
#define DFF_ 2048

#define GMT_ 129            // m tiles

typedef short short8 __attribute__((ext_vector_type(8)));
typedef float floatx4 __attribute__((ext_vector_type(4)));

__device__ __forceinline__ float bf2f(unsigned short u) {
    return __uint_as_float(((unsigned int)u) << 16);
}
__device__ __forceinline__ unsigned short f2b_rne(float f) {
    unsigned int u = __float_as_uint(f);
    unsigned int r = u + 0x7FFF + ((u >> 16) & 1);
    return (unsigned short)(r >> 16);
}
__device__ __forceinline__ void gload16(const void* g, void* l) {
    __builtin_amdgcn_global_load_lds(
        (const __attribute__((address_space(1))) void*)g,
        (__attribute__((address_space(3))) void*)l, 16, 0, 0);
}
// fast tanh via hardware exp: exact at +/-inf, ~1e-6 rel error
__device__ __forceinline__ float tanh_fast(float x) {
    return 1.f - 2.f / (__expf(2.f * x) + 1.f);
}

// ---------------------------------------------------------------- span ids + f32->bf16 weight convert, fused
// blocks [0, B_): span computation; blocks [B_, ...): x4-vectorized 5-segment convert
__global__ void span_f2b5_kernel(const int* __restrict__ pos1, int* __restrict__ span,
                                 const float* __restrict__ s0, const float* __restrict__ s1,
                                 const float* __restrict__ s2, const float* __restrict__ s3,
                                 const float* __restrict__ s4,
                                 unsigned short* __restrict__ dst,
                                 int c0, int c1, int c2, int c3, int c4) {
    int tid = threadIdx.x;
    if (blockIdx.x >= B_) {
        int i = ((blockIdx.x - B_) * 256 + tid) * 4;
        if (i >= c4) return;
        const float* src;
        if      (i < c0) src = s0 + i;
        else if (i < c1) src = s1 + (i - c0);
        else if (i < c2) src = s2 + (i - c1);
        else if (i < c3) src = s3 + (i - c2);
        else             src = s4 + (i - c3);
        float4 v = *(const float4*)src;
        ushort4 o;
        o.x = f2b_rne(v.x); o.y = f2b_rne(v.y); o.z = f2b_rne(v.z); o.w = f2b_rne(v.w);
        *(ushort4*)&dst[i] = o;
        return;
    }
    int b = blockIdx.x;
    __shared__ int st[M_], en[M_];
    __shared__ int redm[4];
    for (int j = tid; j < M_; j += 256) {
        st[j] = pos1[(b * M_ + j) * 2];
        en[j] = pos1[(b * M_ + j) * 2 + 1];
    }
    __syncthreads();
    // parallel first-zero: min index j with en[j]==0 (prefix-validity semantics)
    int idx = M_;
    for (int j = tid; j < M_; j += 256)
        if (en[j] == 0 && j < idx) idx = j;
    for (int off = 32; off; off >>= 1) idx = min(idx, __shfl_down(idx, off));
    if ((tid & 63) == 0) redm[tid >> 6] = idx;
    __syncthreads();
    int n = min(min(redm[0], redm[1]), min(redm[2], redm[3]));
    for (int k = tid; k < M_; k += 256) {
        int best = -1;
        for (int j = 0; j < n; ++j)
            if (st[j] <= k && k < en[j]) best = j;
        span[b * M_ + k] = best;
    }
}

// ---------------------------------------------------------------- build x0 (f32 + bf16 shadow), PE inline
__global__ __launch_bounds__(256) void build_x(const float* __restrict__ emb,
                        const int* __restrict__ pos2,
                        const float* __restrict__ fbase,
                        const int* __restrict__ span,
                        float* __restrict__ x,
                        unsigned short* __restrict__ xb) {
    int gid = blockIdx.x * 256 + threadIdx.x;      // 0 .. T_*64-1
    int t  = gid >> 6;                              // token
    int e0 = (gid & 63) * 8;                        // first of 8 elems
    int s = t % S_;
    int b = t / S_;
    float v[8];
    if (s == 0) {
        float4 a = *(const float4*)&emb[E_ + e0];
        float4 c = *(const float4*)&emb[E_ + e0 + 4];
        v[0]=a.x; v[1]=a.y; v[2]=a.z; v[3]=a.w; v[4]=c.x; v[5]=c.y; v[6]=c.z; v[7]=c.w;
    } else {
        int k = s - 1;
        int sid = span[b * M_ + k];
        if (sid >= 0) {
            int p = pos2[b * M_ + sid];
            const float* er = emb + (size_t)p * E_ + e0;
            float4 a = *(const float4*)er;
            float4 c = *(const float4*)(er + 4);
            v[0]=a.x; v[1]=a.y; v[2]=a.z; v[3]=a.w; v[4]=c.x; v[5]=c.y; v[6]=c.z; v[7]=c.w;
            float fs = (float)sid;
#pragma unroll
            for (int jj = 0; jj < 4; ++jj) {
                float ex = (float)(e0 + 2 * jj) * (1.0f / 512.0f);
                float ang = fs * exp2f(-ex * 13.287712379549449f);   // log2(10000)
                float sn, cs;
                __sincosf(ang, &sn, &cs);
                v[2 * jj]     += sn;
                v[2 * jj + 1] += cs;
            }
        } else {
            const float* fr = fbase + ((size_t)b * M_ + k) * E_ + e0;
            float4 a = *(const float4*)fr;
            float4 c = *(const float4*)(fr + 4);
            v[0]=a.x; v[1]=a.y; v[2]=a.z; v[3]=a.w; v[4]=c.x; v[5]=c.y; v[6]=c.z; v[7]=c.w;
        }
    }
    size_t o = (size_t)t * E_ + e0;
    *(float4*)&x[o]     = make_float4(v[0], v[1], v[2], v[3]);
    *(float4*)&x[o + 4] = make_float4(v[4], v[5], v[6], v[7]);
    short8 ob;
#pragma unroll
    for (int j = 0; j < 8; ++j) ob[j] = (short)f2b_rne(v[j]);
    *(short8*)&xb[o] = ob;
}

// ---------------------------------------------------------------- bf16 MFMA GEMM (NT)
// R8-verified body (best measured: FFN1-class 71.6 us, zero bank conflicts):
// 3 LDS buffers, counted s_waitcnt vmcnt(4) (stage(t+1) stays in flight across
// the barrier; vmcnt(0) only at the last peeled step), chunk-XOR swizzle on BOTH
// sides (pre-swizzled per-lane global source for the linear global_load_lds dest
// + same XOR on ds_read), setprio(1) around the MFMA cluster.
// FIVE falsified departures this session (R3 tile, R4 8-phase, R5 no-LDS, R9
// A-from-global, plus R1-vs-R0 schedule neutral) - do not restructure further.
// ACT==2 fuses the discriminator pos-feature dot (no C store).
template <int ACT, int KT>  // ACT: 0 none 1 relu 2 tanh+zdot(no C write)
__global__ __launch_bounds__(256, 3) void gemm_bf16(const unsigned short* __restrict__ A,
                                                    const unsigned short* __restrict__ W,
                                                    const float* __restrict__ bias,
                                                    unsigned short* __restrict__ Cb,
                                                    int T, int O,
                                                    const float* __restrict__ wdz,
                                                    float* __restrict__ zout) {
    constexpr int K = KT;
    constexpr int NSTEP = K / 32;
    __shared__ __align__(16) unsigned short sA[3][128 * 32];
    __shared__ __align__(16) unsigned short sB[3][128 * 32];
    int tid = threadIdx.x;
    int lane = tid & 63, wv = tid >> 6;
    int wr = (wv >> 1) * 64, wc = (wv & 1) * 64;

    // ---- panel swizzle: 8 m-tiles per panel, n fastest within panel
    int gn = O / 128;
    int per_panel = 8 * gn;
    int id = blockIdx.x;
    int p = id / per_panel;
    int r = id - p * per_panel;
    int mrem = GMT_ - p * 8; if (mrem > 8) mrem = 8;
    int mt = p * 8 + r % mrem;
    int nt = r / mrem;
    int t0 = mt * 128, o0 = nt * 128;

    floatx4 acc[4][4] = {};

    // staging: lane covers row (lane>>2), chunk (lane&3); global chunk pre-swizzled
    // with s(row) = (row>>1)&3 == (lane>>3)&3 (same for row+16).
    int swz_st = (((lane & 3) ^ ((lane >> 3) & 3))) * 8;
    const unsigned short* Ag = A + (size_t)(t0 + wv * 32 + (lane >> 2)) * K + swz_st;
    const unsigned short* Bg = W + (size_t)(o0 + wv * 32 + (lane >> 2)) * K + swz_st;
    const size_t row16 = (size_t)16 * K;
    const int wvo = wv * 1024;

    // fragment read: row = (wr|wc) + i*16 + fr; chunk = fq ^ ((fr>>1)&3)
    int fr = lane & 15;
    int fks = (((lane >> 4) ^ ((lane >> 1) & 3))) * 8;

    auto stage = [&](unsigned short* da, unsigned short* db, int k) {
        gload16(Ag + k, da + wvo);
        gload16(Ag + row16 + k, da + wvo + 512);
        gload16(Bg + k, db + wvo);
        gload16(Bg + row16 + k, db + wvo + 512);
    };
    auto compute = [&](const unsigned short* ca, const unsigned short* cb) {
        short8 af[4], bfr[4];
#pragma unroll
        for (int i = 0; i < 4; ++i)
            af[i] = *(const short8*)&ca[(wr + i * 16 + fr) * 32 + fks];
#pragma unroll
        for (int j = 0; j < 4; ++j)
            bfr[j] = *(const short8*)&cb[(wc + j * 16 + fr) * 32 + fks];
        __builtin_amdgcn_s_setprio(1);
#pragma unroll
        for (int i = 0; i < 4; ++i)
#pragma unroll
            for (int j = 0; j < 4; ++j)
                acc[i][j] = __builtin_amdgcn_mfma_f32_16x16x32_bf16(af[i], bfr[j], acc[i][j], 0, 0, 0);
        __builtin_amdgcn_s_setprio(0);
    };

    unsigned short *a0 = sA[0], *a1 = sA[1], *a2 = sA[2];
    unsigned short *b0 = sB[0], *b1 = sB[1], *b2 = sB[2];

    // prologue: 2 stages in flight (8 vm ops/wave)
    stage(a0, b0, 0);
    stage(a1, b1, 32);

#pragma unroll 3
    for (int t = 0; t < NSTEP - 2; ++t) {
        // wait stage(t) only; stage(t+1)'s 4 loads stay in flight across the barrier
        asm volatile("s_waitcnt vmcnt(4)" ::: "memory");
        __builtin_amdgcn_s_barrier();
        asm volatile("" ::: "memory");
        stage(a2, b2, (t + 2) * 32);   // overwrites slot (t-1)%3: all reads of it done pre-barrier
        compute(a0, b0);
        unsigned short* ta = a0; a0 = a1; a1 = a2; a2 = ta;
        unsigned short* tb = b0; b0 = b1; b1 = b2; b2 = tb;
    }
    // t = NSTEP-2: stage(NSTEP-1) may still be in flight
    asm volatile("s_waitcnt vmcnt(4)" ::: "memory");
    __builtin_amdgcn_s_barrier();
    asm volatile("" ::: "memory");
    compute(a0, b0);
    a0 = a1; b0 = b1;
    // t = NSTEP-1: full drain (only place vmcnt reaches 0)
    asm volatile("s_waitcnt vmcnt(0)" ::: "memory");
    __builtin_amdgcn_s_barrier();
    asm volatile("" ::: "memory");
    compute(a0, b0);

    int cr = (lane >> 4) * 4;
    int cc = lane & 15;
    if (ACT == 2) {
        // fused tanh + z-dot epilogue: zp[i][rr] = sum_j tanh(acc) * wdz[col]
        float zp[4][4];
#pragma unroll
        for (int i = 0; i < 4; ++i)
#pragma unroll
            for (int rr = 0; rr < 4; ++rr) zp[i][rr] = 0.f;
#pragma unroll
        for (int j = 0; j < 4; ++j) {
            int gn_ = o0 + wc + j * 16 + cc;
            float wz = wdz[gn_];
#pragma unroll
            for (int i = 0; i < 4; ++i)
#pragma unroll
                for (int rr = 0; rr < 4; ++rr)
                    zp[i][rr] += tanh_fast(acc[i][j][rr]) * wz;
        }
        // reduce across the 16-lane col group (lanes share rows, differ in cc)
#pragma unroll
        for (int i = 0; i < 4; ++i)
#pragma unroll
            for (int rr = 0; rr < 4; ++rr) {
                float v = zp[i][rr];
                v += __shfl_xor(v, 1);
                v += __shfl_xor(v, 2);
                v += __shfl_xor(v, 4);
                v += __shfl_xor(v, 8);
                if (cc == 0) {
                    int gm_ = t0 + wr + i * 16 + cr + rr;
                    if (gm_ < T) atomicAdd(&zout[gm_], v);
                }
            }
        return;
    }
#pragma unroll
    for (int i = 0; i < 4; ++i) {
#pragma unroll
        for (int j = 0; j < 4; ++j) {
            int gn_ = o0 + wc + j * 16 + cc;
            float bv = bias ? bias[gn_] : 0.f;
#pragma unroll
            for (int rr = 0; rr < 4; ++rr) {
                int gm_ = t0 + wr + i * 16 + cr + rr;
                if (gm_ >= T) continue;
                float v = acc[i][j][rr] + bv;
                if (ACT == 1) v = fmaxf(v, 0.f);
                Cb[(size_t)gm_ * O + gn_] = f2b_rne(v);
            }
        }
    }
}

// ---------------------------------------------------------------- MFMA attention: 4 waves per block
// Previously 4104 single-wave blocks: HW block-slot cap (~16/CU) limited occupancy
// to ~16 waves/CU and each 64B row-gather had no intra-block sharing. Now block b
// covers s = b>>1, h = (b&1)*4 + wv: the 4 waves are 4 heads of the SAME position,
// so their Q/K/V row reads are adjacent 128B slices of the same rows (512B
// contiguous per row at block level, L1/L2 reuse). LDS 30.7KB -> 5 blocks/CU =
// 20 waves/CU. Per-wave compute body byte-identical to the verified R11 version;
// per-wave private vt/ps slices.
__global__ __launch_bounds__(256) void attn_mfma(const unsigned short* __restrict__ qkv,
                                                 unsigned short* __restrict__ o) {
    __shared__ __align__(16) unsigned short vt[4][64 * 40];   // V^T [d][m], stride 40
    __shared__ __align__(16) unsigned short ps[4][32 * 40];   // P [l][m], stride 40
    int wv = threadIdx.x >> 6;
    int lane = threadIdx.x & 63;
    int s = blockIdx.x >> 1;
    int h = ((blockIdx.x & 1) << 2) + wv;
    int hd = h * 64;
    int fr = lane & 15, fq = lane >> 4;
    unsigned short* vtw = vt[wv];
    unsigned short* psw = ps[wv];

    {
        int m = lane >> 1;
        int d0 = (lane & 1) * 32;
        const unsigned short* vrow = qkv + ((size_t)m * S_ + s) * 1536 + 1024 + hd + d0;
        short8 v0 = *(const short8*)(vrow);
        short8 v1 = *(const short8*)(vrow + 8);
        short8 v2 = *(const short8*)(vrow + 16);
        short8 v3 = *(const short8*)(vrow + 24);
#pragma unroll
        for (int j = 0; j < 8; ++j) {
            vtw[(d0 + j) * 40 + m]      = (unsigned short)v0[j];
            vtw[(d0 + 8 + j) * 40 + m]  = (unsigned short)v1[j];
            vtw[(d0 + 16 + j) * 40 + m] = (unsigned short)v2[j];
            vtw[(d0 + 24 + j) * 40 + m] = (unsigned short)v3[j];
        }
    }

    floatx4 c[2][2] = {};
#pragma unroll
    for (int ks = 0; ks < 2; ++ks) {
        short8 aq[2], bk[2];
#pragma unroll
        for (int lt = 0; lt < 2; ++lt) {
            int l = lt * 16 + fr;
            aq[lt] = *(const short8*)(qkv + ((size_t)l * S_ + s) * 1536 + hd + ks * 32 + fq * 8);
        }
#pragma unroll
        for (int mt = 0; mt < 2; ++mt) {
            int m = mt * 16 + fr;
            bk[mt] = *(const short8*)(qkv + ((size_t)m * S_ + s) * 1536 + 512 + hd + ks * 32 + fq * 8);
        }
#pragma unroll
        for (int lt = 0; lt < 2; ++lt)
#pragma unroll
            for (int mt = 0; mt < 2; ++mt)
                c[lt][mt] = __builtin_amdgcn_mfma_f32_16x16x32_bf16(aq[lt], bk[mt], c[lt][mt], 0, 0, 0);
    }

#pragma unroll
    for (int lt = 0; lt < 2; ++lt) {
#pragma unroll
        for (int r = 0; r < 4; ++r) {
            float a = c[lt][0][r] * 0.125f;
            float b = c[lt][1][r] * 0.125f;
            float mx = fmaxf(a, b);
#pragma unroll
            for (int off = 1; off < 16; off <<= 1) mx = fmaxf(mx, __shfl_xor(mx, off));
            float ea = __expf(a - mx), eb = __expf(b - mx);
            float sm = ea + eb;
#pragma unroll
            for (int off = 1; off < 16; off <<= 1) sm += __shfl_xor(sm, off);
            float inv = 1.f / sm;
            int l = lt * 16 + fq * 4 + r;
            psw[l * 40 + fr]      = f2b_rne(ea * inv);
            psw[l * 40 + 16 + fr] = f2b_rne(eb * inv);
        }
    }
    __syncthreads();

    short8 pa[2], vb[4];
#pragma unroll
    for (int lt = 0; lt < 2; ++lt)
        pa[lt] = *(const short8*)&psw[(lt * 16 + fr) * 40 + fq * 8];
#pragma unroll
    for (int dt = 0; dt < 4; ++dt)
        vb[dt] = *(const short8*)&vtw[(dt * 16 + fr) * 40 + fq * 8];

    floatx4 oa[2][4] = {};
#pragma unroll
    for (int lt = 0; lt < 2; ++lt)
#pragma unroll
        for (int dt = 0; dt < 4; ++dt)
            oa[lt][dt] = __builtin_amdgcn_mfma_f32_16x16x32_bf16(pa[lt], vb[dt], oa[lt][dt], 0, 0, 0);

#pragma unroll
    for (int lt = 0; lt < 2; ++lt)
#pragma unroll
        for (int dt = 0; dt < 4; ++dt)
#pragma unroll
            for (int r = 0; r < 4; ++r) {
                int l = lt * 16 + fq * 4 + r;
                o[((size_t)l * S_ + s) * E_ + hd + dt * 16 + fr] = f2b_rne(oa[lt][dt][r]);
            }
}

// ---------------------------------------------------------------- x = LN(x + h); wave-per-token (64 lanes x 8 elems)
// WX=false skips the f32 x write (dead after the last LN - only xb is read later).
template <bool WX>
__global__ __launch_bounds__(256) void add_ln(float* __restrict__ x,
                                              unsigned short* __restrict__ xb,
                                              const unsigned short* __restrict__ h,
                                              const float* __restrict__ w,
                                              const float* __restrict__ b) {
    int t = (blockIdx.x << 2) + (threadIdx.x >> 6);   // token (grid = T_/4 blocks)
    int lane = threadIdx.x & 63;
    int i0 = lane * 8;
    float* xr = x + (size_t)t * E_;
    const unsigned short* hr = h + (size_t)t * E_;
    float4 xv0 = *(const float4*)&xr[i0];
    float4 xv1 = *(const float4*)&xr[i0 + 4];
    short8 hv = *(const short8*)&hr[i0];
    float v[8];
    v[0] = xv0.x + bf2f((unsigned short)hv[0]);
    v[1] = xv0.y + bf2f((unsigned short)hv[1]);
    v[2] = xv0.z + bf2f((unsigned short)hv[2]);
    v[3] = xv0.w + bf2f((unsigned short)hv[3]);
    v[4] = xv1.x + bf2f((unsigned short)hv[4]);
    v[5] = xv1.y + bf2f((unsigned short)hv[5]);
    v[6] = xv1.z + bf2f((unsigned short)hv[6]);
    v[7] = xv1.w + bf2f((unsigned short)hv[7]);

    float sum = 0.f;
#pragma unroll
    for (int j = 0; j < 8; ++j) sum += v[j];
#pragma unroll
    for (int off = 32; off; off >>= 1) sum += __shfl_xor(sum, off);
    float mu = sum * (1.0f / E_);

    float qs = 0.f;
#pragma unroll
    for (int j = 0; j < 8; ++j) { float d = v[j] - mu; qs += d * d; }
#pragma unroll
    for (int off = 32; off; off >>= 1) qs += __shfl_xor(qs, off);
    float rstd = rsqrtf(qs * (1.0f / E_) + 1e-5f);

    float4 wv0 = *(const float4*)&w[i0];
    float4 wv1 = *(const float4*)&w[i0 + 4];
    float4 bv0 = *(const float4*)&b[i0];
    float4 bv1 = *(const float4*)&b[i0 + 4];
    float o[8];
    o[0] = (v[0] - mu) * rstd * wv0.x + bv0.x;
    o[1] = (v[1] - mu) * rstd * wv0.y + bv0.y;
    o[2] = (v[2] - mu) * rstd * wv0.z + bv0.z;
    o[3] = (v[3] - mu) * rstd * wv0.w + bv0.w;
    o[4] = (v[4] - mu) * rstd * wv1.x + bv1.x;
    o[5] = (v[5] - mu) * rstd * wv1.y + bv1.y;
    o[6] = (v[6] - mu) * rstd * wv1.z + bv1.z;
    o[7] = (v[7] - mu) * rstd * wv1.w + bv1.w;
    if (WX) {
        *(float4*)&xr[i0]     = make_float4(o[0], o[1], o[2], o[3]);
        *(float4*)&xr[i0 + 4] = make_float4(o[4], o[5], o[6], o[7]);
    }
    short8 ob;
#pragma unroll
    for (int j = 0; j < 8; ++j) ob[j] = (short)f2b_rne(o[j]);
    *(short8*)&xb[(size_t)t * E_ + i0] = ob;
}

// ---------------------------------------------------------------- discriminator + sigmoid, wave-per-token
__global__ __launch_bounds__(256) void disc_kernel(const float* __restrict__ bert,
                                                   const float* __restrict__ z,
                                                   const float* __restrict__ wd,
                                                   const float* __restrict__ bd,
                                                   float* __restrict__ out) {
    int t = (blockIdx.x << 2) + (threadIdx.x >> 6);   // grid = T_/4 blocks
    int lane = threadIdx.x & 63;
    int i0 = lane * 12;                               // 64 * 12 = 768
    const float* br = bert + (size_t)t * F_ + i0;
    const float* wr = wd + i0;
    float s = 0.f;
#pragma unroll
    for (int j = 0; j < 12; j += 4) {
        float4 bv = *(const float4*)(br + j);
        float4 wv = *(const float4*)(wr + j);
        s += bv.x * wv.x + bv.y * wv.y + bv.z * wv.z + bv.w * wv.w;
    }
#pragma unroll
    for (int off = 32; off; off >>= 1) s += __shfl_xor(s, off);
    if (lane == 0) {
        float zz = s + z[t] + bd[0];
        out[t] = 1.f / (1.f + __expf(-zz));
    }
}

// ---------------------------------------------------------------- launch
extern "C" void kernel_launch(void* const* d_in, const int* in_sizes, int n_in,
                              void* d_out, int out_size, void* d_ws, size_t ws_size,
                              hipStream_t stream) {
    const int*   pos1 = (const int*)d_in[0];
    const int*   pos2 = (const int*)d_in[1];
    const float* bert = (const float*)d_in[2];
    const float* fb   = (const float*)d_in[3];
    const float* emb  = (const float*)d_in[4];
    const float* wi   = (const float*)d_in[5];
    const float* bi   = (const float*)d_in[6];
    const float* wo   = (const float*)d_in[7];
    const float* bo   = (const float*)d_in[8];
    const float* ln1w = (const float*)d_in[9];
    const float* ln1b = (const float*)d_in[10];
    const float* ln2w = (const float*)d_in[11];
    const float* ln2b = (const float*)d_in[12];
    const float* w1   = (const float*)d_in[13];
    const float* b1   = (const float*)d_in[14];
    const float* w2   = (const float*)d_in[15];
    const float* b2   = (const float*)d_in[16];
    const float* wm   = (const float*)d_in[17];
    const float* wd   = (const float*)d_in[18];
    const float* bd   = (const float*)d_in[19];
    float* out = (float*)d_out;

    // workspace layout
    float* ws   = (float*)d_ws;
    int*   span = (int*)ws;                                   // 16384 i
    float* x    = ws + 16384;                                 // T_*512 f
    unsigned short* xb  = (unsigned short*)(x + (size_t)T_ * 512);   // TP_*512 bf16
    unsigned short* atb = xb + (size_t)TP_ * 512;                    // TP_*512 bf16
    unsigned short* hb  = atb + (size_t)TP_ * 512;                   // T_*512 bf16
    unsigned short* U   = hb + (size_t)T_ * 512;              // union: qkv | h1
    unsigned short* qkvb = U;
    unsigned short* h1b  = U;
    unsigned short* wib  = U + (size_t)TP_ * 2048;            // weights bf16, contiguous
    const int NWI = 2 * 1536 * 512;
    const int NWO = 2 * 512 * 512;
    const int NW1 = 2 * 2048 * 512;
    const int NW2 = 2 * 512 * 2048;
    const int NWM = 768 * 512;
    unsigned short* wob = wib + NWI;
    unsigned short* w1b = wob + NWO;
    unsigned short* w2b = w1b + NW1;
    unsigned short* wmb = w2b + NW2;
    // z (T_ f32) aliases atb: atb is dead after the layer-2 WO GEMM reads it.
    float* z = (float*)atb;

    {
        int c0 = NWI, c1 = c0 + NWO, c2 = c1 + NW1, c3 = c2 + NW2, c4 = c3 + NWM;
        int nf = (c4 / 4 + 255) / 256;
        span_f2b5_kernel<<<B_ + nf, 256, 0, stream>>>(pos1, span, wi, wo, w1, w2, wm, wib,
                                                      c0, c1, c2, c3, c4);
    }
    build_x<<<T_ / 4, 256, 0, stream>>>(emb, pos2, fb, span, x, xb);

    for (int l = 0; l < 2; ++l) {
        gemm_bf16<0, 512><<<GMT_ * (1536 / 128), 256, 0, stream>>>(
            xb, wib + (size_t)l * 1536 * 512, bi + l * 1536, qkvb, T_, 1536, nullptr, nullptr);
        attn_mfma<<<S_ * 2, 256, 0, stream>>>(qkvb, atb);
        gemm_bf16<0, 512><<<GMT_ * (512 / 128), 256, 0, stream>>>(
            atb, wob + (size_t)l * 512 * 512, bo + l * 512, hb, T_, 512, nullptr, nullptr);
        add_ln<true><<<T_ / 4, 256, 0, stream>>>(x, xb, hb, ln1w + l * 512, ln1b + l * 512);
        gemm_bf16<1, 512><<<GMT_ * (2048 / 128), 256, 0, stream>>>(
            xb, w1b + (size_t)l * 2048 * 512, b1 + l * 2048, h1b, T_, 2048, nullptr, nullptr);
        gemm_bf16<0, 2048><<<GMT_ * (512 / 128), 256, 0, stream>>>(
            h1b, w2b + (size_t)l * 512 * 2048, b2 + l * 512, hb, T_, 512, nullptr, nullptr);
        if (l == 0)
            add_ln<true><<<T_ / 4, 256, 0, stream>>>(x, xb, hb, ln2w + l * 512, ln2b + l * 512);
        else
            add_ln<false><<<T_ / 4, 256, 0, stream>>>(x, xb, hb, ln2w + l * 512, ln2b + l * 512);
    }
    // atb now dead -> reuse as z accumulator for the fused final GEMM + disc dot
    hipMemsetAsync(z, 0, (size_t)T_ * sizeof(float), stream);
    gemm_bf16<2, 512><<<GMT_ * (768 / 128), 256, 0, stream>>>(
        xb, wmb, nullptr, nullptr, T_, 768, wd + F_, z);
    disc_kernel<<<T_ / 4, 256, 0, stream>>>(bert, z, wd, bd, out);
}